// Round 12
// baseline (265.184 us; speedup 1.0000x reference)
//
#include <hip/hip_runtime.h>
#include <hip/hip_bf16.h>
#include <math.h>

// float32(np.e) exactly: 0x402DF854
#define E32 2.7182817459106445f

__device__ __forceinline__ unsigned long long packkey(float vf, int idx) {
  unsigned u = __float_as_uint(vf);
  u = (u & 0x80000000u) ? ~u : (u | 0x80000000u);
  return (((unsigned long long)u) << 32) | (unsigned)idx;
}
__device__ __forceinline__ float unpackval(unsigned long long k) {
  unsigned m = (unsigned)(k >> 32);
  m = (m & 0x80000000u) ? (m ^ 0x80000000u) : ~m;
  return __uint_as_float(m);
}

// ---------------------------------------------------------------------------
// Stage 1: one tanh per thread; store tanh value + per-block max|tanh|.
// ---------------------------------------------------------------------------
__global__ __launch_bounds__(256) void tanh_max_kernel(
    const float* __restrict__ w2, const float* __restrict__ w3,
    const float* __restrict__ w4, const float* __restrict__ w5,
    float* __restrict__ tanhbuf, float* __restrict__ partials) {
  int blk = blockIdx.x;
  const float* w; int base_blk, tbase;
  if (blk < 36)       { w = w2; base_blk = 0;   tbase = 0; }
  else if (blk < 72)  { w = w3; base_blk = 36;  tbase = 9216; }
  else if (blk < 144) { w = w4; base_blk = 72;  tbase = 18432; }
  else                { w = w5; base_blk = 144; tbase = 36864; }
  int i = (blk - base_blk) * 256 + threadIdx.x;
  float t = tanhf(w[i]);
  tanhbuf[tbase + i] = t;
  __shared__ float red[256];
  red[threadIdx.x] = fabsf(t);
  __syncthreads();
  for (int s = 128; s > 0; s >>= 1) {
    if (threadIdx.x < s) red[threadIdx.x] = fmaxf(red[threadIdx.x], red[threadIdx.x + s]);
    __syncthreads();
  }
  if (threadIdx.x == 0) partials[blk] = red[0];
}

// ---------------------------------------------------------------------------
// Stage 2: reduce tensor's partials -> alpha; quantize one element/thread.
// ---------------------------------------------------------------------------
__global__ __launch_bounds__(256) void quant2_kernel(
    const float* __restrict__ tanhbuf, const float* __restrict__ partials,
    float* __restrict__ q2, float* __restrict__ q3,
    float* __restrict__ q4, float* __restrict__ q5) {
  int blk = blockIdx.x;
  float* dst; int base_blk, tbase, pb0, pb1, F, N;
  if (blk < 36)       { dst = q2; base_blk = 0;   tbase = 0;     pb0 = 0;   pb1 = 36;  F = 32; N = 288; }
  else if (blk < 72)  { dst = q3; base_blk = 36;  tbase = 9216;  pb0 = 36;  pb1 = 72;  F = 32; N = 288; }
  else if (blk < 144) { dst = q4; base_blk = 72;  tbase = 18432; pb0 = 72;  pb1 = 144; F = 64; N = 288; }
  else                { dst = q5; base_blk = 144; tbase = 36864; pb0 = 144; pb1 = 288; F = 64; N = 576; }
  __shared__ float red[256];
  float mx = 0.0f;
  for (int j = pb0 + threadIdx.x; j < pb1; j += 256) mx = fmaxf(mx, partials[j]);
  red[threadIdx.x] = mx;
  __syncthreads();
  for (int s = 128; s > 0; s >>= 1) {
    if (threadIdx.x < s) red[threadIdx.x] = fmaxf(red[threadIdx.x], red[threadIdx.x + s]);
    __syncthreads();
  }
  float a = red[0];
  int i = (blk - base_blk) * 256 + threadIdx.x;
  float t = tanhbuf[tbase + i];
  int f = i / N, n = i % N;
  float r = fminf(fmaxf(t / a, -1.0f), 1.0f) * 127.0f;
  dst[n * F + f] = rintf(r) * a / 127.0f;
}

// ---------------------------------------------------------------------------
// Transpose FC weights: wfcT[n*10 + f] = wfc[f*4096 + n]  (pure copy)
// ---------------------------------------------------------------------------
__global__ __launch_bounds__(256) void transpose_wfc_kernel(
    const float* __restrict__ wfc, float* __restrict__ wfcT) {
  int o = blockIdx.x * 256 + threadIdx.x;
  if (o >= 40960) return;
  int n = o / 10, f = o % 10;
  wfcT[o] = wfc[f * 4096 + n];
}

// ---------------------------------------------------------------------------
// conv1 + BN + ReLU + maxpool2 + min(.,1) + exp
// ---------------------------------------------------------------------------
__global__ __launch_bounds__(256) void conv1_kernel(
    const float* __restrict__ inp, const float* __restrict__ w,
    const float* __restrict__ g, const float* __restrict__ bb,
    const float* __restrict__ m, const float* __restrict__ vv,
    float* __restrict__ z1) {
  int idx = blockIdx.x * 256 + threadIdx.x;
  if (idx >= 8 * 32 * 32 * 32) return;
  int x = idx & 31, y = (idx >> 5) & 31, c = (idx >> 10) & 31, b = idx >> 15;
  float scale = g[c] / sqrtf(vv[c] + 1e-5f);
  float bias = bb[c];
  float mean = m[c];
  float mx = -3.402823466e38f;
  for (int dy = 0; dy < 2; ++dy) {
    for (int dx = 0; dx < 2; ++dx) {
      int oy = 2 * y + dy, ox = 2 * x + dx;
      float acc = 0.0f;
      for (int kh = 0; kh < 5; ++kh) {
        int r = oy + kh - 2;
        if (r < 0 || r >= 64) continue;
        for (int kw = 0; kw < 5; ++kw) {
          int cc2 = ox + kw - 2;
          if (cc2 < 0 || cc2 >= 64) continue;
          acc += w[c * 25 + kh * 5 + kw] * inp[(b * 64 + r) * 64 + cc2];
        }
      }
      float xs = (acc - mean) * scale + bias;
      xs = fmaxf(xs, 0.0f);
      mx = fmaxf(mx, xs);
    }
  }
  mx = fminf(mx, 1.0f);
  z1[idx] = (mx == 1.0f) ? E32 : expf(mx);
}

// ---------------------------------------------------------------------------
// min_pool3 (3x3, stride 2, pad 1 w/ 1e5)
// ---------------------------------------------------------------------------
__global__ __launch_bounds__(256) void mp3_kernel(
    const float* __restrict__ in, float* __restrict__ out, int BC, int H) {
  int OH = H >> 1;
  int total = BC * OH * OH;
  int idx = blockIdx.x * 256 + threadIdx.x;
  if (idx >= total) return;
  int j = idx % OH, i = (idx / OH) % OH, bc = idx / (OH * OH);
  float mn = 100000.0f;
  for (int di = 0; di < 3; ++di) {
    int r = 2 * i - 1 + di;
    if (r < 0 || r >= H) continue;
    for (int dj = 0; dj < 3; ++dj) {
      int cc = 2 * j - 1 + dj;
      if (cc < 0 || cc >= H) continue;
      mn = fminf(mn, in[bc * H * H + r * H + cc]);
    }
  }
  out[idx] = mn;
}

// min_pool3 over (a*b) computed on the fly
__global__ __launch_bounds__(256) void mp3mul_kernel(
    const float* __restrict__ a, const float* __restrict__ b2,
    float* __restrict__ out, int BC, int H) {
  int OH = H >> 1;
  int total = BC * OH * OH;
  int idx = blockIdx.x * 256 + threadIdx.x;
  if (idx >= total) return;
  int j = idx % OH, i = (idx / OH) % OH, bc = idx / (OH * OH);
  float mn = 100000.0f;
  for (int di = 0; di < 3; ++di) {
    int r = 2 * i - 1 + di;
    if (r < 0 || r >= H) continue;
    for (int dj = 0; dj < 3; ++dj) {
      int cc = 2 * j - 1 + dj;
      if (cc < 0 || cc >= H) continue;
      int q = bc * H * H + r * H + cc;
      mn = fminf(mn, __fmul_rn(a[q], b2[q]));
    }
  }
  out[idx] = mn;
}

// ---------------------------------------------------------------------------
// t_conv: one block (T threads) per patch. (unchanged — passing)
// ---------------------------------------------------------------------------
template <int CIN, int F, int S, int HIN, bool MUL, int T>
__global__ __launch_bounds__(T, 1) void tconv_kernel(
    const float* __restrict__ in, const float* __restrict__ in2,
    const float* __restrict__ wqt, float* __restrict__ out, float MST) {
  constexpr int N = CIN * 9;
  constexpr int OH = (HIN - 1) / S + 1;
  constexpr int P = OH * OH;
  constexpr int K = (N + T - 1) / T;
  constexpr int NCH = N / 32;

  __shared__ unsigned long long pk[N];
  __shared__ float sval[N + 1];
  __shared__ unsigned short sidx[N];
  __shared__ float wbuf[2][32 * F];
  __shared__ float wc[NCH][F];
  __shared__ float iwc[NCH][F];
  __shared__ float pmin[F * NCH];

  int blk = blockIdx.x;
  int b = blk / P, p = blk % P;
  int ph = p / OH, pw = p % OH;
  int tid = threadIdx.x;

  // Phase 0: patch keys
  for (int n = tid; n < N; n += T) {
    int c = n / 9, kk = n % 9, kh = kk / 3, kw = kk % 3;
    int r = ph * S + kh - 1, cc = pw * S + kw - 1;
    float v = 0.0f;
    if (r >= 0 && r < HIN && cc >= 0 && cc < HIN) {
      int q = ((b * CIN + c) * HIN + r) * HIN + cc;
      v = MUL ? __fmul_rn(in[q], in2[q]) : in[q];
    }
    pk[n] = packkey((v < 0.1f) ? MST : v, n);
  }
  if (tid == 0) sval[N] = 1.0f;
  __syncthreads();

  // Phase 1: rank sort, LDS broadcast j-loop (batched 8-wide)
  unsigned long long mine[K];
  int rnk[K];
#pragma unroll
  for (int k = 0; k < K; ++k) {
    int i = tid + T * k;
    mine[k] = (i < N) ? pk[i] : ~0ull;
    rnk[k] = 0;
  }
  for (int j0 = 0; j0 < N; j0 += 8) {
    unsigned long long u[8];
#pragma unroll
    for (int r = 0; r < 8; ++r) u[r] = pk[j0 + r];
#pragma unroll
    for (int r = 0; r < 8; ++r) {
#pragma unroll
      for (int k = 0; k < K; ++k) rnk[k] += (u[r] < mine[k]) ? 1 : 0;
    }
  }
#pragma unroll
  for (int k = 0; k < K; ++k) {
    int i = tid + T * k;
    if (i < N) {
      sval[rnk[k]] = unpackval(mine[k]);
      sidx[rnk[k]] = (unsigned short)(mine[k] & 0xffffull);
    }
  }
  __syncthreads();

  // Phase 2a: stage chunk 0 (all threads)
  for (int t = tid; t < 32 * F; t += T) {
    int q = t / F, f = t % F;
    wbuf[0][t] = wqt[(int)sidx[q] * F + f];
  }
  __syncthreads();

  // Phase 2b: pass A — wave 0 chains, other waves stage next chunk
  float wsum = 0.0f, iwsum = 0.0f;
  for (int c = 0; c < NCH; ++c) {
    if (tid >= 64 && c + 1 < NCH) {
      int i0n = (c + 1) * 32;
      float* nb = wbuf[(c + 1) & 1];
      for (int t = tid - 64; t < 32 * F; t += (T - 64)) {
        int q = t / F, f = t % F;
        nb[t] = wqt[(int)sidx[i0n + q] * F + f];
      }
    }
    if (tid < F) {
      const float* wb = wbuf[c & 1];
      wc[c][tid] = wsum;
      iwc[c][tid] = iwsum;
      int i0 = c * 32;
#pragma unroll
      for (int q0 = 0; q0 < 32; q0 += 8) {
        float w8[8], s8[8];
#pragma unroll
        for (int r = 0; r < 8; ++r) {
          w8[r] = wb[(q0 + r) * F + tid];
          s8[r] = sval[i0 + q0 + r];
        }
#pragma unroll
        for (int r = 0; r < 8; ++r) {
          wsum = __fadd_rn(wsum, w8[r]);
          iwsum = __fadd_rn(iwsum, __fmul_rn(s8[r], w8[r]));
        }
      }
    }
    __syncthreads();
  }

  // Phase 2c: replay — NCH*F parallel tasks, bit-exact per element
  for (int task = tid; task < NCH * F; task += T) {
    int c = task / F, f = task % F;
    float ws = wc[c][f], iws = iwc[c][f], omin = 3.402823466e38f;
    int i0 = c * 32;
#pragma unroll
    for (int q0 = 0; q0 < 32; q0 += 8) {
      float wv8[8], sv8[8], nv8[8];
#pragma unroll
      for (int r = 0; r < 8; ++r) {
        int i = i0 + q0 + r;
        wv8[r] = wqt[(int)sidx[i] * F + f];
        sv8[r] = sval[i];
        nv8[r] = sval[i + 1];
      }
#pragma unroll
      for (int r = 0; r < 8; ++r) {
        ws = __fadd_rn(ws, wv8[r]);
        iws = __fadd_rn(iws, __fmul_rn(sv8[r], wv8[r]));
        float den = fminf(fmaxf(__fadd_rn(ws, -1.0f), 1e-10f), 1e10f);
        float oa = iws / den;
        float o = (ws < 1.0f) ? MST : oa;
        o = (o < sv8[r]) ? MST : o;
        o = (o > nv8[r]) ? MST : o;  // t_linear_c: strict >
        omin = fminf(omin, o);
      }
    }
    pmin[f * NCH + c] = omin;
  }
  __syncthreads();

  // Phase 2d: min across chunks (order-free), write out
  if (tid < F) {
    float m2 = pmin[tid * NCH];
#pragma unroll
    for (int c = 1; c < NCH; ++c) m2 = fminf(m2, pmin[tid * NCH + c]);
    out[(b * F + tid) * P + p] = m2;
  }
}

// ---------------------------------------------------------------------------
// FC sort kernel: 8 blocks x 512. Register-resident bitonic sort with a
// COMPACT runtime loop (small I$ footprint). Same comparator network as the
// fully-unrolled version -> bit-identical order. Writes sval/sidx to global.
// ---------------------------------------------------------------------------
#define CE(x, y) { int i_ = (tid << 3) + (x); \
  bool up_ = (((i_ >> lk) & 1) == 0); \
  unsigned long long a_ = k[(x)], c_ = k[(y)]; \
  if ((a_ > c_) == up_) { k[(x)] = c_; k[(y)] = a_; } }

__global__ __launch_bounds__(512, 1) void fc_sort_kernel(
    const float* __restrict__ z5, const float* __restrict__ m3,
    float* __restrict__ svalG, unsigned short* __restrict__ sidxG) {
  __shared__ __align__(16) unsigned long long keys[4096];
  int b = blockIdx.x, tid = threadIdx.x, lane = tid & 63;

  unsigned long long k[8];
  {
    int c = tid >> 3, p0 = (tid << 3) & 63;
    const float4* z4p = (const float4*)(z5 + (b * 64 + c) * 64 + p0);
    const float4* m4p = (const float4*)(m3 + (b * 32 + (c & 31)) * 64 + p0);
    float4 za = z4p[0], zb = z4p[1], ma = m4p[0], mb = m4p[1];
    int n0 = tid << 3;
    k[0] = packkey(__fmul_rn(za.x, ma.x), n0 + 0);
    k[1] = packkey(__fmul_rn(za.y, ma.y), n0 + 1);
    k[2] = packkey(__fmul_rn(za.z, ma.z), n0 + 2);
    k[3] = packkey(__fmul_rn(za.w, ma.w), n0 + 3);
    k[4] = packkey(__fmul_rn(zb.x, mb.x), n0 + 4);
    k[5] = packkey(__fmul_rn(zb.y, mb.y), n0 + 5);
    k[6] = packkey(__fmul_rn(zb.z, mb.z), n0 + 6);
    k[7] = packkey(__fmul_rn(zb.w, mb.w), n0 + 7);
  }

  for (int lk = 1; lk <= 12; ++lk) {
    for (int lj = lk - 1; lj >= 0; --lj) {
      if (lj >= 9) {
        int pm = 1 << (lj - 3);
#pragma unroll
        for (int m = 0; m < 8; ++m) keys[m * 512 + tid] = k[m];
        __syncthreads();
        bool lower = ((tid & pm) == 0);
        bool up = (((tid >> (lk - 3)) & 1) == 0);
        bool wmin = (lower == up);
#pragma unroll
        for (int m = 0; m < 8; ++m) {
          unsigned long long o = keys[m * 512 + (tid ^ pm)];
          unsigned long long mine = k[m];
          k[m] = wmin ? (mine < o ? mine : o) : (mine > o ? mine : o);
        }
        __syncthreads();
      } else if (lj >= 3) {
        int lm = 1 << (lj - 3);
        bool lower = ((lane & lm) == 0);
        bool up = (((tid >> (lk - 3)) & 1) == 0);
        bool wmin = (lower == up);
#pragma unroll
        for (int m = 0; m < 8; ++m) {
          unsigned long long o = __shfl_xor(k[m], lm, 64);
          unsigned long long mine = k[m];
          k[m] = wmin ? (mine < o ? mine : o) : (mine > o ? mine : o);
        }
      } else if (lj == 2) {
        CE(0, 4) CE(1, 5) CE(2, 6) CE(3, 7)
      } else if (lj == 1) {
        CE(0, 2) CE(1, 3) CE(4, 6) CE(5, 7)
      } else {
        CE(0, 1) CE(2, 3) CE(4, 5) CE(6, 7)
      }
    }
  }

  // write sorted values/indices to global (coalesced 16B stores)
  {
    float4 v0, v1;
    v0.x = unpackval(k[0]); v0.y = unpackval(k[1]);
    v0.z = unpackval(k[2]); v0.w = unpackval(k[3]);
    v1.x = unpackval(k[4]); v1.y = unpackval(k[5]);
    v1.z = unpackval(k[6]); v1.w = unpackval(k[7]);
    float* svalRow = svalG + b * 4104;
    ((float4*)svalRow)[tid * 2] = v0;
    ((float4*)svalRow)[tid * 2 + 1] = v1;
    ushort si[8];
#pragma unroll
    for (int m = 0; m < 8; ++m) si[m] = (unsigned short)(k[m] & 0xffffull);
    ((ulong2*)(sidxG + b * 4096))[tid] = *(ulong2*)si;
    if (tid == 0) svalRow[4096] = 1.0f;
  }
}
#undef CE

// ---------------------------------------------------------------------------
// FC scan kernel: 8 blocks x 512. Loads sval/sidx from global into LDS, then
// pass-A carry chain (wave 0 chains, waves 1-7 stage wfcT into LDS) +
// bit-exact parallel replay. Identical arithmetic to the R10/R11 fc.
// ---------------------------------------------------------------------------
__global__ __launch_bounds__(512, 1) void fc_scan_kernel(
    const float* __restrict__ svalG, const unsigned short* __restrict__ sidxG,
    const float* __restrict__ wfcT, float* __restrict__ out) {
  constexpr int NN = 4096;
  __shared__ __align__(16) float sval[NN + 1];
  __shared__ __align__(16) unsigned short sidx[NN];
  __shared__ __align__(16) float wstage[2][2608];
  __shared__ float wc[64][10];
  __shared__ float iwc[64][10];
  __shared__ float pmin[64][10];

  int b = blockIdx.x, tid = threadIdx.x;
  const float* svalRow = svalG + b * 4104;

  // load sorted data into LDS (coalesced)
  for (int t = tid; t < 1024; t += 512)
    ((float4*)sval)[t] = ((const float4*)svalRow)[t];
  ((ulong2*)sidx)[tid] = ((const ulong2*)(sidxG + b * 4096))[tid];
  if (tid == 0) sval[NN] = svalRow[4096];
  __syncthreads();

  // prologue: stage chunk 0 into wstage[0] — batched loads
  {
    float tmp[5];
#pragma unroll
    for (int u = 0; u < 5; ++u) {
      int t = tid + u * 512;
      tmp[u] = wfcT[(int)sidx[t / 10] * 10 + (t % 10)];
    }
#pragma unroll
    for (int u = 0; u < 5; ++u) {
      int t = tid + u * 512;
      wstage[0][(t % 10) * 260 + t / 10] = tmp[u];
    }
  }
  __syncthreads();

  // pass A: 16 chunks of 256; waves 1-7 stage next chunk, wave 0 chains
  float wsum = 0.0f, iwsum = 0.0f;
  for (int c = 0; c < 16; ++c) {
    int c0 = c * 256;
    const float* cur = wstage[c & 1];
    float* nxt = wstage[(c & 1) ^ 1];
    if (tid >= 64 && c + 1 < 16) {
      int c0n = c0 + 256;
      float tmp[6];
#pragma unroll
      for (int u = 0; u < 6; ++u) {
        int t = (tid - 64) + u * 448;
        tmp[u] = (t < 2560) ? wfcT[(int)sidx[c0n + t / 10] * 10 + (t % 10)] : 0.0f;
      }
#pragma unroll
      for (int u = 0; u < 6; ++u) {
        int t = (tid - 64) + u * 448;
        if (t < 2560) nxt[(t % 10) * 260 + t / 10] = tmp[u];
      }
    }
    if (tid < 10) {
      const float* wrow = cur + tid * 260;
      float4 wA4[4], sA4[4], wB4[4], sB4[4];
      auto LD = [&](int i0, float4* w4, float4* s4) {
#pragma unroll
        for (int kq = 0; kq < 4; ++kq) {
          w4[kq] = *(const float4*)(wrow + i0 + 4 * kq);
          s4[kq] = *(const float4*)(sval + c0 + i0 + 4 * kq);
        }
      };
      auto ACC = [&](const float4* w4, const float4* s4) {
#pragma unroll
        for (int kq = 0; kq < 4; ++kq) {
          float w0 = w4[kq].x, w1 = w4[kq].y, w2 = w4[kq].z, w3 = w4[kq].w;
          float s0 = s4[kq].x, s1 = s4[kq].y, s2 = s4[kq].z, s3 = s4[kq].w;
          wsum = __fadd_rn(wsum, w0); iwsum = __fadd_rn(iwsum, __fmul_rn(s0, w0));
          wsum = __fadd_rn(wsum, w1); iwsum = __fadd_rn(iwsum, __fmul_rn(s1, w1));
          wsum = __fadd_rn(wsum, w2); iwsum = __fadd_rn(iwsum, __fmul_rn(s2, w2));
          wsum = __fadd_rn(wsum, w3); iwsum = __fadd_rn(iwsum, __fmul_rn(s3, w3));
        }
      };
      LD(0, wA4, sA4);
      for (int i0 = 0; i0 < 256; i0 += 32) {
        if ((i0 & 63) == 0) {
          int cc = (c0 + i0) >> 6;
          wc[cc][tid] = wsum;
          iwc[cc][tid] = iwsum;
        }
        LD(i0 + 16, wB4, sB4);
        ACC(wA4, sA4);
        if (i0 + 32 < 256) LD(i0 + 32, wA4, sA4);
        ACC(wB4, sB4);
      }
    }
    __syncthreads();
  }

  // replay: 64 chunks x 10 neurons, bit-exact per element
  const float MST = 4.0f * E32;
  for (int task = tid; task < 640; task += 512) {
    int c = task / 10, f = task % 10;
    float wsr = wc[c][f], iwsr = iwc[c][f], omin = 3.402823466e38f;
    int i0 = c * 64;
    for (int q0 = 0; q0 < 64; q0 += 8) {
      float wv8[8], sv8[8], nv8[8];
#pragma unroll
      for (int r = 0; r < 8; ++r) {
        int i = i0 + q0 + r;
        wv8[r] = wfcT[(int)sidx[i] * 10 + f];
        sv8[r] = sval[i];
        nv8[r] = sval[i + 1];
      }
#pragma unroll
      for (int r = 0; r < 8; ++r) {
        wsr = __fadd_rn(wsr, wv8[r]);
        iwsr = __fadd_rn(iwsr, __fmul_rn(sv8[r], wv8[r]));
        float den = fminf(fmaxf(__fadd_rn(wsr, -1.0f), 1e-10f), 1e10f);
        float oa = iwsr / den;
        float o = (wsr < 1.0f) ? MST : oa;
        o = (o < sv8[r]) ? MST : o;
        o = (o >= nv8[r]) ? MST : o;  // t_linear: >=
        omin = fminf(omin, o);
      }
    }
    pmin[c][f] = omin;
  }
  __syncthreads();

  if (tid < 10) {
    float m = pmin[0][tid];
#pragma unroll
    for (int c = 1; c < 64; ++c) m = fminf(m, pmin[c][tid]);
    out[b * 10 + tid] = m;
  }
}

// ---------------------------------------------------------------------------
extern "C" void kernel_launch(void* const* d_in, const int* in_sizes, int n_in,
                              void* d_out, int out_size, void* d_ws, size_t ws_size,
                              hipStream_t stream) {
  const float* inp   = (const float*)d_in[0];
  const float* w1    = (const float*)d_in[1];
  const float* bn_g  = (const float*)d_in[2];
  const float* bn_b  = (const float*)d_in[3];
  const float* bn_m  = (const float*)d_in[4];
  const float* bn_v  = (const float*)d_in[5];
  const float* w2    = (const float*)d_in[6];
  const float* w3    = (const float*)d_in[7];
  const float* w4    = (const float*)d_in[8];
  const float* w5    = (const float*)d_in[9];
  const float* wfc   = (const float*)d_in[10];
  float* out = (float*)d_out;

  float* ws = (float*)d_ws;
  float* wq2 = ws + 16;          // 9216
  float* wq3 = wq2 + 9216;       // 9216
  float* wq4 = wq3 + 9216;       // 18432
  float* wq5 = wq4 + 18432;      // 36864
  float* z1  = wq5 + 36864;      // 262144
  float* m1  = z1 + 262144;      // 65536
  float* z2  = m1 + 65536;       // 65536
  float* z3  = z2 + 65536;       // 65536
  float* m3  = z3 + 65536;       // 16384
  float* z4  = m3 + 16384;       // 32768
  float* z5  = z4 + 32768;       // 32768
  float* tanhbuf  = z5 + 32768;  // 73728
  float* partials = tanhbuf + 73728;  // 288 (pad 512)
  float* wfcT = partials + 512;  // 40960
  float* svalG = wfcT + 40960;   // 8*4104 = 32832
  unsigned short* sidxG = (unsigned short*)(svalG + 32832);  // 8*4096 u16

  tanh_max_kernel<<<288, 256, 0, stream>>>(w2, w3, w4, w5, tanhbuf, partials);
  quant2_kernel<<<288, 256, 0, stream>>>(tanhbuf, partials, wq2, wq3, wq4, wq5);
  transpose_wfc_kernel<<<160, 256, 0, stream>>>(wfc, wfcT);

  conv1_kernel<<<1024, 256, 0, stream>>>(inp, w1, bn_g, bn_b, bn_m, bn_v, z1);
  mp3_kernel<<<256, 256, 0, stream>>>(z1, m1, 8 * 32, 32);

  tconv_kernel<32, 32, 2, 32, false, 320><<<8 * 256, 320, 0, stream>>>(z1, nullptr, wq2, z2, E32);
  tconv_kernel<32, 32, 1, 16, false, 320><<<8 * 256, 320, 0, stream>>>(z2, nullptr, wq3, z3, E32);
  mp3mul_kernel<<<64, 256, 0, stream>>>(z3, m1, m3, 8 * 32, 16);
  tconv_kernel<32, 64, 2, 16, true, 512><<<8 * 64, 512, 0, stream>>>(z3, m1, wq4, z4, 2.0f * E32);
  tconv_kernel<64, 64, 1, 8, false, 512><<<8 * 64, 512, 0, stream>>>(z4, nullptr, wq5, z5, 2.0f * E32);

  fc_sort_kernel<<<8, 512, 0, stream>>>(z5, m3, svalG, sidxG);
  fc_scan_kernel<<<8, 512, 0, stream>>>(svalG, sidxG, wfcT, out);
}

// Round 13
// 255.301 us; speedup vs baseline: 1.0387x; 1.0387x over previous
//
#include <hip/hip_runtime.h>
#include <hip/hip_bf16.h>
#include <math.h>

// float32(np.e) exactly: 0x402DF854
#define E32 2.7182817459106445f

__device__ __forceinline__ unsigned long long packkey(float vf, int idx) {
  unsigned u = __float_as_uint(vf);
  u = (u & 0x80000000u) ? ~u : (u | 0x80000000u);
  return (((unsigned long long)u) << 32) | (unsigned)idx;
}
__device__ __forceinline__ float unpackval(unsigned long long k) {
  unsigned m = (unsigned)(k >> 32);
  m = (m & 0x80000000u) ? (m ^ 0x80000000u) : ~m;
  return __uint_as_float(m);
}

// ---------------------------------------------------------------------------
// Stage 1: one tanh per thread; store tanh value + per-block max|tanh|.
// ---------------------------------------------------------------------------
__global__ __launch_bounds__(256) void tanh_max_kernel(
    const float* __restrict__ w2, const float* __restrict__ w3,
    const float* __restrict__ w4, const float* __restrict__ w5,
    float* __restrict__ tanhbuf, float* __restrict__ partials) {
  int blk = blockIdx.x;
  const float* w; int base_blk, tbase;
  if (blk < 36)       { w = w2; base_blk = 0;   tbase = 0; }
  else if (blk < 72)  { w = w3; base_blk = 36;  tbase = 9216; }
  else if (blk < 144) { w = w4; base_blk = 72;  tbase = 18432; }
  else                { w = w5; base_blk = 144; tbase = 36864; }
  int i = (blk - base_blk) * 256 + threadIdx.x;
  float t = tanhf(w[i]);
  tanhbuf[tbase + i] = t;
  __shared__ float red[256];
  red[threadIdx.x] = fabsf(t);
  __syncthreads();
  for (int s = 128; s > 0; s >>= 1) {
    if (threadIdx.x < s) red[threadIdx.x] = fmaxf(red[threadIdx.x], red[threadIdx.x + s]);
    __syncthreads();
  }
  if (threadIdx.x == 0) partials[blk] = red[0];
}

// ---------------------------------------------------------------------------
// Stage 2 (fused): blocks [0,288) quantize (reduce partials -> alpha, one
// element per thread); blocks [288,448) transpose wfc -> wfcT.
// ---------------------------------------------------------------------------
__global__ __launch_bounds__(256) void quantT_kernel(
    const float* __restrict__ tanhbuf, const float* __restrict__ partials,
    float* __restrict__ q2, float* __restrict__ q3,
    float* __restrict__ q4, float* __restrict__ q5,
    const float* __restrict__ wfc, float* __restrict__ wfcT) {
  int blk = blockIdx.x;
  if (blk >= 288) {
    int o = (blk - 288) * 256 + threadIdx.x;
    if (o < 40960) {
      int n = o / 10, f = o % 10;
      wfcT[o] = wfc[f * 4096 + n];
    }
    return;
  }
  float* dst; int base_blk, tbase, pb0, pb1, F, N;
  if (blk < 36)       { dst = q2; base_blk = 0;   tbase = 0;     pb0 = 0;   pb1 = 36;  F = 32; N = 288; }
  else if (blk < 72)  { dst = q3; base_blk = 36;  tbase = 9216;  pb0 = 36;  pb1 = 72;  F = 32; N = 288; }
  else if (blk < 144) { dst = q4; base_blk = 72;  tbase = 18432; pb0 = 72;  pb1 = 144; F = 64; N = 288; }
  else                { dst = q5; base_blk = 144; tbase = 36864; pb0 = 144; pb1 = 288; F = 64; N = 576; }
  __shared__ float red[256];
  float mx = 0.0f;
  for (int j = pb0 + threadIdx.x; j < pb1; j += 256) mx = fmaxf(mx, partials[j]);
  red[threadIdx.x] = mx;
  __syncthreads();
  for (int s = 128; s > 0; s >>= 1) {
    if (threadIdx.x < s) red[threadIdx.x] = fmaxf(red[threadIdx.x], red[threadIdx.x + s]);
    __syncthreads();
  }
  float a = red[0];
  int i = (blk - base_blk) * 256 + threadIdx.x;
  float t = tanhbuf[tbase + i];
  int f = i / N, n = i % N;
  float r = fminf(fmaxf(t / a, -1.0f), 1.0f) * 127.0f;
  dst[n * F + f] = rintf(r) * a / 127.0f;
}

// ---------------------------------------------------------------------------
// conv1 + BN + ReLU + maxpool2 + min(.,1) + exp
// ---------------------------------------------------------------------------
__global__ __launch_bounds__(256) void conv1_kernel(
    const float* __restrict__ inp, const float* __restrict__ w,
    const float* __restrict__ g, const float* __restrict__ bb,
    const float* __restrict__ m, const float* __restrict__ vv,
    float* __restrict__ z1) {
  int idx = blockIdx.x * 256 + threadIdx.x;
  if (idx >= 8 * 32 * 32 * 32) return;
  int x = idx & 31, y = (idx >> 5) & 31, c = (idx >> 10) & 31, b = idx >> 15;
  float scale = g[c] / sqrtf(vv[c] + 1e-5f);
  float bias = bb[c];
  float mean = m[c];
  float mx = -3.402823466e38f;
  for (int dy = 0; dy < 2; ++dy) {
    for (int dx = 0; dx < 2; ++dx) {
      int oy = 2 * y + dy, ox = 2 * x + dx;
      float acc = 0.0f;
      for (int kh = 0; kh < 5; ++kh) {
        int r = oy + kh - 2;
        if (r < 0 || r >= 64) continue;
        for (int kw = 0; kw < 5; ++kw) {
          int cc2 = ox + kw - 2;
          if (cc2 < 0 || cc2 >= 64) continue;
          acc += w[c * 25 + kh * 5 + kw] * inp[(b * 64 + r) * 64 + cc2];
        }
      }
      float xs = (acc - mean) * scale + bias;
      xs = fmaxf(xs, 0.0f);
      mx = fmaxf(mx, xs);
    }
  }
  mx = fminf(mx, 1.0f);
  z1[idx] = (mx == 1.0f) ? E32 : expf(mx);
}

// ---------------------------------------------------------------------------
// min_pool3 (3x3, stride 2, pad 1 w/ 1e5)
// ---------------------------------------------------------------------------
__global__ __launch_bounds__(256) void mp3_kernel(
    const float* __restrict__ in, float* __restrict__ out, int BC, int H) {
  int OH = H >> 1;
  int total = BC * OH * OH;
  int idx = blockIdx.x * 256 + threadIdx.x;
  if (idx >= total) return;
  int j = idx % OH, i = (idx / OH) % OH, bc = idx / (OH * OH);
  float mn = 100000.0f;
  for (int di = 0; di < 3; ++di) {
    int r = 2 * i - 1 + di;
    if (r < 0 || r >= H) continue;
    for (int dj = 0; dj < 3; ++dj) {
      int cc = 2 * j - 1 + dj;
      if (cc < 0 || cc >= H) continue;
      mn = fminf(mn, in[bc * H * H + r * H + cc]);
    }
  }
  out[idx] = mn;
}

// min_pool3 over (a*b) computed on the fly
__global__ __launch_bounds__(256) void mp3mul_kernel(
    const float* __restrict__ a, const float* __restrict__ b2,
    float* __restrict__ out, int BC, int H) {
  int OH = H >> 1;
  int total = BC * OH * OH;
  int idx = blockIdx.x * 256 + threadIdx.x;
  if (idx >= total) return;
  int j = idx % OH, i = (idx / OH) % OH, bc = idx / (OH * OH);
  float mn = 100000.0f;
  for (int di = 0; di < 3; ++di) {
    int r = 2 * i - 1 + di;
    if (r < 0 || r >= H) continue;
    for (int dj = 0; dj < 3; ++dj) {
      int cc = 2 * j - 1 + dj;
      if (cc < 0 || cc >= H) continue;
      int q = bc * H * H + r * H + cc;
      mn = fminf(mn, __fmul_rn(a[q], b2[q]));
    }
  }
  out[idx] = mn;
}

// ---------------------------------------------------------------------------
// t_conv: one block (512 threads) per patch.
//  Phase 1: register-resident bitonic sort (keys padded to NP, 1-2/thread,
//           compact runtime loop; shuffle intra-wave, element-major LDS
//           cross-wave). Unique keys -> same order as stable rank sort.
//  Phase 2: carry-replay scan (unchanged).
// ---------------------------------------------------------------------------
template <int CIN, int F, int S, int HIN, bool MUL>
__global__ __launch_bounds__(512, 1) void tconv_kernel(
    const float* __restrict__ in, const float* __restrict__ in2,
    const float* __restrict__ wqt, float* __restrict__ out, float MST) {
  constexpr int N = CIN * 9;
  constexpr int NP = (N <= 512) ? 512 : 1024;
  constexpr int KP = NP / 512;
  constexpr int OH = (HIN - 1) / S + 1;
  constexpr int P = OH * OH;
  constexpr int T = 512;
  constexpr int NCH = N / 32;

  __shared__ __align__(16) unsigned long long pk[NP];
  __shared__ float sval[N + 1];
  __shared__ unsigned short sidx[N];
  __shared__ float wbuf[2][32 * F];
  __shared__ float wc[NCH][F];
  __shared__ float iwc[NCH][F];
  __shared__ float pmin[F * NCH];

  int blk = blockIdx.x;
  int b = blk / P, p = blk % P;
  int ph = p / OH, pw = p % OH;
  int tid = threadIdx.x;

  // Phase 0: patch keys (+inf pad beyond N)
  for (int n = tid; n < NP; n += T) {
    if (n < N) {
      int c = n / 9, kk = n % 9, kh = kk / 3, kw = kk % 3;
      int r = ph * S + kh - 1, cc = pw * S + kw - 1;
      float v = 0.0f;
      if (r >= 0 && r < HIN && cc >= 0 && cc < HIN) {
        int q = ((b * CIN + c) * HIN + r) * HIN + cc;
        v = MUL ? __fmul_rn(in[q], in2[q]) : in[q];
      }
      pk[n] = packkey((v < 0.1f) ? MST : v, n);
    } else {
      pk[n] = ~0ull;
    }
  }
  if (tid == 0) sval[N] = 1.0f;
  __syncthreads();

  // Phase 1: bitonic sort
  if constexpr (KP == 1) {
    unsigned long long k0 = pk[tid];
    __syncthreads();
    for (int lk = 1; lk <= 9; ++lk) {
      for (int lj = lk - 1; lj >= 0; --lj) {
        int j = 1 << lj;
        bool up = ((tid >> lk) & 1) == 0;
        bool wmin = (((tid & j) == 0) == up);
        unsigned long long o;
        if (lj >= 6) {
          pk[tid] = k0;
          __syncthreads();
          o = pk[tid ^ j];
          __syncthreads();
        } else {
          o = __shfl_xor(k0, j, 64);
        }
        k0 = wmin ? (k0 < o ? k0 : o) : (k0 > o ? k0 : o);
      }
    }
    if (tid < N) {
      sval[tid] = unpackval(k0);
      sidx[tid] = (unsigned short)(k0 & 0xffffull);
    }
  } else {
    unsigned long long k0 = pk[2 * tid], k1 = pk[2 * tid + 1];
    __syncthreads();
    for (int lk = 1; lk <= 10; ++lk) {
      for (int lj = lk - 1; lj >= 0; --lj) {
        bool up = ((tid >> (lk - 1)) & 1) == 0;  // = ((i>>lk)&1)==0, i=2*tid+m
        if (lj == 0) {
          if ((k0 > k1) == up) { unsigned long long t2 = k0; k0 = k1; k1 = t2; }
        } else {
          int tj = 1 << (lj - 1);
          bool wmin = (((tid & tj) == 0) == up);
          unsigned long long o0, o1;
          if (lj >= 7) {
            pk[tid] = k0; pk[512 + tid] = k1;
            __syncthreads();
            o0 = pk[tid ^ tj]; o1 = pk[512 + (tid ^ tj)];
            __syncthreads();
          } else {
            o0 = __shfl_xor(k0, tj, 64);
            o1 = __shfl_xor(k1, tj, 64);
          }
          k0 = wmin ? (k0 < o0 ? k0 : o0) : (k0 > o0 ? k0 : o0);
          k1 = wmin ? (k1 < o1 ? k1 : o1) : (k1 > o1 ? k1 : o1);
        }
      }
    }
    int i0 = tid * 2;
    if (i0 < N) {
      sval[i0] = unpackval(k0);
      sidx[i0] = (unsigned short)(k0 & 0xffffull);
    }
    if (i0 + 1 < N) {
      sval[i0 + 1] = unpackval(k1);
      sidx[i0 + 1] = (unsigned short)(k1 & 0xffffull);
    }
  }
  __syncthreads();

  // Phase 2a: stage chunk 0 (all threads)
  for (int t = tid; t < 32 * F; t += T) {
    int q = t / F, f = t % F;
    wbuf[0][t] = wqt[(int)sidx[q] * F + f];
  }
  __syncthreads();

  // Phase 2b: pass A — wave 0 chains, other waves stage next chunk
  float wsum = 0.0f, iwsum = 0.0f;
  for (int c = 0; c < NCH; ++c) {
    if (tid >= 64 && c + 1 < NCH) {
      int i0n = (c + 1) * 32;
      float* nb = wbuf[(c + 1) & 1];
      for (int t = tid - 64; t < 32 * F; t += (T - 64)) {
        int q = t / F, f = t % F;
        nb[t] = wqt[(int)sidx[i0n + q] * F + f];
      }
    }
    if (tid < F) {
      const float* wb = wbuf[c & 1];
      wc[c][tid] = wsum;
      iwc[c][tid] = iwsum;
      int i0 = c * 32;
#pragma unroll
      for (int q0 = 0; q0 < 32; q0 += 8) {
        float w8[8], s8[8];
#pragma unroll
        for (int r = 0; r < 8; ++r) {
          w8[r] = wb[(q0 + r) * F + tid];
          s8[r] = sval[i0 + q0 + r];
        }
#pragma unroll
        for (int r = 0; r < 8; ++r) {
          wsum = __fadd_rn(wsum, w8[r]);
          iwsum = __fadd_rn(iwsum, __fmul_rn(s8[r], w8[r]));
        }
      }
    }
    __syncthreads();
  }

  // Phase 2c: replay — NCH*F parallel tasks, bit-exact per element
  for (int task = tid; task < NCH * F; task += T) {
    int c = task / F, f = task % F;
    float ws = wc[c][f], iws = iwc[c][f], omin = 3.402823466e38f;
    int i0 = c * 32;
#pragma unroll
    for (int q0 = 0; q0 < 32; q0 += 8) {
      float wv8[8], sv8[8], nv8[8];
#pragma unroll
      for (int r = 0; r < 8; ++r) {
        int i = i0 + q0 + r;
        wv8[r] = wqt[(int)sidx[i] * F + f];
        sv8[r] = sval[i];
        nv8[r] = sval[i + 1];
      }
#pragma unroll
      for (int r = 0; r < 8; ++r) {
        ws = __fadd_rn(ws, wv8[r]);
        iws = __fadd_rn(iws, __fmul_rn(sv8[r], wv8[r]));
        float den = fminf(fmaxf(__fadd_rn(ws, -1.0f), 1e-10f), 1e10f);
        float oa = iws / den;
        float o = (ws < 1.0f) ? MST : oa;
        o = (o < sv8[r]) ? MST : o;
        o = (o > nv8[r]) ? MST : o;  // t_linear_c: strict >
        omin = fminf(omin, o);
      }
    }
    pmin[f * NCH + c] = omin;
  }
  __syncthreads();

  // Phase 2d: min across chunks (order-free), write out
  if (tid < F) {
    float m2 = pmin[tid * NCH];
#pragma unroll
    for (int c = 1; c < NCH; ++c) m2 = fminf(m2, pmin[tid * NCH + c]);
    out[(b * F + tid) * P + p] = m2;
  }
}

// ---------------------------------------------------------------------------
// FC t_linear: single kernel, 8 blocks x 512. Compact-loop register bitonic
// sort (8 keys/thread) + pass-A carry chain + bit-exact parallel replay.
// ---------------------------------------------------------------------------
#define CE(x, y) { int i_ = (tid << 3) + (x); \
  bool up_ = (((i_ >> lk) & 1) == 0); \
  unsigned long long a_ = k[(x)], c_ = k[(y)]; \
  if ((a_ > c_) == up_) { k[(x)] = c_; k[(y)] = a_; } }

__global__ __launch_bounds__(512, 1) void fc_kernel(
    const float* __restrict__ z5, const float* __restrict__ m3,
    const float* __restrict__ wfcT, float* __restrict__ out) {
  constexpr int NN = 4096;
  __shared__ __align__(16) unsigned long long keys[NN];  // 32 KB (multi-use)
  __shared__ __align__(16) float sval[NN + 1];
  __shared__ __align__(16) unsigned short sidx[NN];
  __shared__ float wc[64][10];
  __shared__ float iwc[64][10];
  __shared__ float pmin[64][10];
  float* wsA = (float*)keys;          // [10][260] buffer 0 (pass A stage)
  float* wsB = (float*)keys + 2608;   // [10][260] buffer 1

  int b = blockIdx.x, tid = threadIdx.x, lane = tid & 63;

  unsigned long long k[8];
  {
    int c = tid >> 3, p0 = (tid << 3) & 63;
    const float4* z4p = (const float4*)(z5 + (b * 64 + c) * 64 + p0);
    const float4* m4p = (const float4*)(m3 + (b * 32 + (c & 31)) * 64 + p0);
    float4 za = z4p[0], zb = z4p[1], ma = m4p[0], mb = m4p[1];
    int n0 = tid << 3;
    k[0] = packkey(__fmul_rn(za.x, ma.x), n0 + 0);
    k[1] = packkey(__fmul_rn(za.y, ma.y), n0 + 1);
    k[2] = packkey(__fmul_rn(za.z, ma.z), n0 + 2);
    k[3] = packkey(__fmul_rn(za.w, ma.w), n0 + 3);
    k[4] = packkey(__fmul_rn(zb.x, mb.x), n0 + 4);
    k[5] = packkey(__fmul_rn(zb.y, mb.y), n0 + 5);
    k[6] = packkey(__fmul_rn(zb.z, mb.z), n0 + 6);
    k[7] = packkey(__fmul_rn(zb.w, mb.w), n0 + 7);
  }

  for (int lk = 1; lk <= 12; ++lk) {
    for (int lj = lk - 1; lj >= 0; --lj) {
      if (lj >= 9) {
        int pm = 1 << (lj - 3);
#pragma unroll
        for (int m = 0; m < 8; ++m) keys[m * 512 + tid] = k[m];
        __syncthreads();
        bool lower = ((tid & pm) == 0);
        bool up = (((tid >> (lk - 3)) & 1) == 0);
        bool wmin = (lower == up);
#pragma unroll
        for (int m = 0; m < 8; ++m) {
          unsigned long long o = keys[m * 512 + (tid ^ pm)];
          unsigned long long mine = k[m];
          k[m] = wmin ? (mine < o ? mine : o) : (mine > o ? mine : o);
        }
        __syncthreads();
      } else if (lj >= 3) {
        int lm = 1 << (lj - 3);
        bool lower = ((lane & lm) == 0);
        bool up = (((tid >> (lk - 3)) & 1) == 0);
        bool wmin = (lower == up);
#pragma unroll
        for (int m = 0; m < 8; ++m) {
          unsigned long long o = __shfl_xor(k[m], lm, 64);
          unsigned long long mine = k[m];
          k[m] = wmin ? (mine < o ? mine : o) : (mine > o ? mine : o);
        }
      } else if (lj == 2) {
        CE(0, 4) CE(1, 5) CE(2, 6) CE(3, 7)
      } else if (lj == 1) {
        CE(0, 2) CE(1, 3) CE(4, 6) CE(5, 7)
      } else {
        CE(0, 1) CE(2, 3) CE(4, 5) CE(6, 7)
      }
    }
  }

  {
    float4 v0, v1;
    v0.x = unpackval(k[0]); v0.y = unpackval(k[1]);
    v0.z = unpackval(k[2]); v0.w = unpackval(k[3]);
    v1.x = unpackval(k[4]); v1.y = unpackval(k[5]);
    v1.z = unpackval(k[6]); v1.w = unpackval(k[7]);
    ((float4*)sval)[tid * 2] = v0;
    ((float4*)sval)[tid * 2 + 1] = v1;
    ushort si[8];
#pragma unroll
    for (int m = 0; m < 8; ++m) si[m] = (unsigned short)(k[m] & 0xffffull);
    ((ulong2*)sidx)[tid] = *(ulong2*)si;
  }
  if (tid == 0) sval[NN] = 1.0f;
  __syncthreads();

  // prologue: stage chunk 0 into wsA — batched loads
  {
    float tmp[5];
#pragma unroll
    for (int u = 0; u < 5; ++u) {
      int t = tid + u * 512;
      tmp[u] = wfcT[(int)sidx[t / 10] * 10 + (t % 10)];
    }
#pragma unroll
    for (int u = 0; u < 5; ++u) {
      int t = tid + u * 512;
      wsA[(t % 10) * 260 + t / 10] = tmp[u];
    }
  }
  __syncthreads();

  // pass A: 16 chunks of 256; waves 1-7 stage next chunk, wave 0 chains
  float wsum = 0.0f, iwsum = 0.0f;
  for (int c = 0; c < 16; ++c) {
    int c0 = c * 256;
    float* cur = (c & 1) ? wsB : wsA;
    float* nxt = (c & 1) ? wsA : wsB;
    if (tid >= 64 && c + 1 < 16) {
      int c0n = c0 + 256;
      float tmp[6];
#pragma unroll
      for (int u = 0; u < 6; ++u) {
        int t = (tid - 64) + u * 448;
        tmp[u] = (t < 2560) ? wfcT[(int)sidx[c0n + t / 10] * 10 + (t % 10)] : 0.0f;
      }
#pragma unroll
      for (int u = 0; u < 6; ++u) {
        int t = (tid - 64) + u * 448;
        if (t < 2560) nxt[(t % 10) * 260 + t / 10] = tmp[u];
      }
    }
    if (tid < 10) {
      const float* wrow = cur + tid * 260;
      float4 wA4[4], sA4[4], wB4[4], sB4[4];
      auto LD = [&](int i0, float4* w4, float4* s4) {
#pragma unroll
        for (int kq = 0; kq < 4; ++kq) {
          w4[kq] = *(const float4*)(wrow + i0 + 4 * kq);
          s4[kq] = *(const float4*)(sval + c0 + i0 + 4 * kq);
        }
      };
      auto ACC = [&](const float4* w4, const float4* s4) {
#pragma unroll
        for (int kq = 0; kq < 4; ++kq) {
          float w0 = w4[kq].x, w1 = w4[kq].y, w2 = w4[kq].z, w3 = w4[kq].w;
          float s0 = s4[kq].x, s1 = s4[kq].y, s2 = s4[kq].z, s3 = s4[kq].w;
          wsum = __fadd_rn(wsum, w0); iwsum = __fadd_rn(iwsum, __fmul_rn(s0, w0));
          wsum = __fadd_rn(wsum, w1); iwsum = __fadd_rn(iwsum, __fmul_rn(s1, w1));
          wsum = __fadd_rn(wsum, w2); iwsum = __fadd_rn(iwsum, __fmul_rn(s2, w2));
          wsum = __fadd_rn(wsum, w3); iwsum = __fadd_rn(iwsum, __fmul_rn(s3, w3));
        }
      };
      LD(0, wA4, sA4);
      for (int i0 = 0; i0 < 256; i0 += 32) {
        if ((i0 & 63) == 0) {
          int cc = (c0 + i0) >> 6;
          wc[cc][tid] = wsum;
          iwc[cc][tid] = iwsum;
        }
        LD(i0 + 16, wB4, sB4);
        ACC(wA4, sA4);
        if (i0 + 32 < 256) LD(i0 + 32, wA4, sA4);
        ACC(wB4, sB4);
      }
    }
    __syncthreads();
  }

  // replay: 64 chunks x 10 neurons, bit-exact per element
  const float MST = 4.0f * E32;
  for (int task = tid; task < 640; task += 512) {
    int c = task / 10, f = task % 10;
    float wsr = wc[c][f], iwsr = iwc[c][f], omin = 3.402823466e38f;
    int i0 = c * 64;
    for (int q0 = 0; q0 < 64; q0 += 8) {
      float wv8[8], sv8[8], nv8[8];
#pragma unroll
      for (int r = 0; r < 8; ++r) {
        int i = i0 + q0 + r;
        wv8[r] = wfcT[(int)sidx[i] * 10 + f];
        sv8[r] = sval[i];
        nv8[r] = sval[i + 1];
      }
#pragma unroll
      for (int r = 0; r < 8; ++r) {
        wsr = __fadd_rn(wsr, wv8[r]);
        iwsr = __fadd_rn(iwsr, __fmul_rn(sv8[r], wv8[r]));
        float den = fminf(fmaxf(__fadd_rn(wsr, -1.0f), 1e-10f), 1e10f);
        float oa = iwsr / den;
        float o = (wsr < 1.0f) ? MST : oa;
        o = (o < sv8[r]) ? MST : o;
        o = (o >= nv8[r]) ? MST : o;  // t_linear: >=
        omin = fminf(omin, o);
      }
    }
    pmin[c][f] = omin;
  }
  __syncthreads();

  if (tid < 10) {
    float m = pmin[0][tid];
#pragma unroll
    for (int c = 1; c < 64; ++c) m = fminf(m, pmin[c][tid]);
    out[b * 10 + tid] = m;
  }
}
#undef CE

// ---------------------------------------------------------------------------
extern "C" void kernel_launch(void* const* d_in, const int* in_sizes, int n_in,
                              void* d_out, int out_size, void* d_ws, size_t ws_size,
                              hipStream_t stream) {
  const float* inp   = (const float*)d_in[0];
  const float* w1    = (const float*)d_in[1];
  const float* bn_g  = (const float*)d_in[2];
  const float* bn_b  = (const float*)d_in[3];
  const float* bn_m  = (const float*)d_in[4];
  const float* bn_v  = (const float*)d_in[5];
  const float* w2    = (const float*)d_in[6];
  const float* w3    = (const float*)d_in[7];
  const float* w4    = (const float*)d_in[8];
  const float* w5    = (const float*)d_in[9];
  const float* wfc   = (const float*)d_in[10];
  float* out = (float*)d_out;

  float* ws = (float*)d_ws;
  float* wq2 = ws + 16;          // 9216
  float* wq3 = wq2 + 9216;       // 9216
  float* wq4 = wq3 + 9216;       // 18432
  float* wq5 = wq4 + 18432;      // 36864
  float* z1  = wq5 + 36864;      // 262144
  float* m1  = z1 + 262144;      // 65536
  float* z2  = m1 + 65536;       // 65536
  float* z3  = z2 + 65536;       // 65536
  float* m3  = z3 + 65536;       // 16384
  float* z4  = m3 + 16384;       // 32768
  float* z5  = z4 + 32768;       // 32768
  float* tanhbuf  = z5 + 32768;  // 73728
  float* partials = tanhbuf + 73728;  // 288 (pad 512)
  float* wfcT = partials + 512;  // 40960

  tanh_max_kernel<<<288, 256, 0, stream>>>(w2, w3, w4, w5, tanhbuf, partials);
  quantT_kernel<<<448, 256, 0, stream>>>(tanhbuf, partials, wq2, wq3, wq4, wq5, wfc, wfcT);

  conv1_kernel<<<1024, 256, 0, stream>>>(inp, w1, bn_g, bn_b, bn_m, bn_v, z1);
  mp3_kernel<<<256, 256, 0, stream>>>(z1, m1, 8 * 32, 32);

  tconv_kernel<32, 32, 2, 32, false><<<8 * 256, 512, 0, stream>>>(z1, nullptr, wq2, z2, E32);
  tconv_kernel<32, 32, 1, 16, false><<<8 * 256, 512, 0, stream>>>(z2, nullptr, wq3, z3, E32);
  mp3mul_kernel<<<64, 256, 0, stream>>>(z3, m1, m3, 8 * 32, 16);
  tconv_kernel<32, 64, 2, 16, true><<<8 * 64, 512, 0, stream>>>(z3, m1, wq4, z4, 2.0f * E32);
  tconv_kernel<64, 64, 1, 8, false><<<8 * 64, 512, 0, stream>>>(z4, nullptr, wq5, z5, 2.0f * E32);

  fc_kernel<<<8, 512, 0, stream>>>(z5, m3, wfcT, out);
}

// Round 14
// 251.066 us; speedup vs baseline: 1.0562x; 1.0169x over previous
//
#include <hip/hip_runtime.h>
#include <hip/hip_bf16.h>
#include <math.h>

// float32(np.e) exactly: 0x402DF854
#define E32 2.7182817459106445f

__device__ __forceinline__ unsigned long long packkey(float vf, int idx) {
  unsigned u = __float_as_uint(vf);
  u = (u & 0x80000000u) ? ~u : (u | 0x80000000u);
  return (((unsigned long long)u) << 32) | (unsigned)idx;
}
__device__ __forceinline__ float unpackval(unsigned long long k) {
  unsigned m = (unsigned)(k >> 32);
  m = (m & 0x80000000u) ? (m ^ 0x80000000u) : ~m;
  return __uint_as_float(m);
}

// ---------------------------------------------------------------------------
// Stage 1: one tanh per thread; store tanh value + per-block max|tanh|.
// ---------------------------------------------------------------------------
__global__ __launch_bounds__(256) void tanh_max_kernel(
    const float* __restrict__ w2, const float* __restrict__ w3,
    const float* __restrict__ w4, const float* __restrict__ w5,
    float* __restrict__ tanhbuf, float* __restrict__ partials) {
  int blk = blockIdx.x;
  const float* w; int base_blk, tbase;
  if (blk < 36)       { w = w2; base_blk = 0;   tbase = 0; }
  else if (blk < 72)  { w = w3; base_blk = 36;  tbase = 9216; }
  else if (blk < 144) { w = w4; base_blk = 72;  tbase = 18432; }
  else                { w = w5; base_blk = 144; tbase = 36864; }
  int i = (blk - base_blk) * 256 + threadIdx.x;
  float t = tanhf(w[i]);
  tanhbuf[tbase + i] = t;
  __shared__ float red[256];
  red[threadIdx.x] = fabsf(t);
  __syncthreads();
  for (int s = 128; s > 0; s >>= 1) {
    if (threadIdx.x < s) red[threadIdx.x] = fmaxf(red[threadIdx.x], red[threadIdx.x + s]);
    __syncthreads();
  }
  if (threadIdx.x == 0) partials[blk] = red[0];
}

// ---------------------------------------------------------------------------
// Stage 2 (fused): blocks [0,288) quantize; blocks [288,448) transpose wfc.
// ---------------------------------------------------------------------------
__global__ __launch_bounds__(256) void quantT_kernel(
    const float* __restrict__ tanhbuf, const float* __restrict__ partials,
    float* __restrict__ q2, float* __restrict__ q3,
    float* __restrict__ q4, float* __restrict__ q5,
    const float* __restrict__ wfc, float* __restrict__ wfcT) {
  int blk = blockIdx.x;
  if (blk >= 288) {
    int o = (blk - 288) * 256 + threadIdx.x;
    if (o < 40960) {
      int n = o / 10, f = o % 10;
      wfcT[o] = wfc[f * 4096 + n];
    }
    return;
  }
  float* dst; int base_blk, tbase, pb0, pb1, F, N;
  if (blk < 36)       { dst = q2; base_blk = 0;   tbase = 0;     pb0 = 0;   pb1 = 36;  F = 32; N = 288; }
  else if (blk < 72)  { dst = q3; base_blk = 36;  tbase = 9216;  pb0 = 36;  pb1 = 72;  F = 32; N = 288; }
  else if (blk < 144) { dst = q4; base_blk = 72;  tbase = 18432; pb0 = 72;  pb1 = 144; F = 64; N = 288; }
  else                { dst = q5; base_blk = 144; tbase = 36864; pb0 = 144; pb1 = 288; F = 64; N = 576; }
  __shared__ float red[256];
  float mx = 0.0f;
  for (int j = pb0 + threadIdx.x; j < pb1; j += 256) mx = fmaxf(mx, partials[j]);
  red[threadIdx.x] = mx;
  __syncthreads();
  for (int s = 128; s > 0; s >>= 1) {
    if (threadIdx.x < s) red[threadIdx.x] = fmaxf(red[threadIdx.x], red[threadIdx.x + s]);
    __syncthreads();
  }
  float a = red[0];
  int i = (blk - base_blk) * 256 + threadIdx.x;
  float t = tanhbuf[tbase + i];
  int f = i / N, n = i % N;
  float r = fminf(fmaxf(t / a, -1.0f), 1.0f) * 127.0f;
  dst[n * F + f] = rintf(r) * a / 127.0f;
}

// ---------------------------------------------------------------------------
// conv1 + BN + ReLU + maxpool2 + min(.,1) + exp
// ---------------------------------------------------------------------------
__global__ __launch_bounds__(256) void conv1_kernel(
    const float* __restrict__ inp, const float* __restrict__ w,
    const float* __restrict__ g, const float* __restrict__ bb,
    const float* __restrict__ m, const float* __restrict__ vv,
    float* __restrict__ z1) {
  int idx = blockIdx.x * 256 + threadIdx.x;
  if (idx >= 8 * 32 * 32 * 32) return;
  int x = idx & 31, y = (idx >> 5) & 31, c = (idx >> 10) & 31, b = idx >> 15;
  float scale = g[c] / sqrtf(vv[c] + 1e-5f);
  float bias = bb[c];
  float mean = m[c];
  float mx = -3.402823466e38f;
  for (int dy = 0; dy < 2; ++dy) {
    for (int dx = 0; dx < 2; ++dx) {
      int oy = 2 * y + dy, ox = 2 * x + dx;
      float acc = 0.0f;
      for (int kh = 0; kh < 5; ++kh) {
        int r = oy + kh - 2;
        if (r < 0 || r >= 64) continue;
        for (int kw = 0; kw < 5; ++kw) {
          int cc2 = ox + kw - 2;
          if (cc2 < 0 || cc2 >= 64) continue;
          acc += w[c * 25 + kh * 5 + kw] * inp[(b * 64 + r) * 64 + cc2];
        }
      }
      float xs = (acc - mean) * scale + bias;
      xs = fmaxf(xs, 0.0f);
      mx = fmaxf(mx, xs);
    }
  }
  mx = fminf(mx, 1.0f);
  z1[idx] = (mx == 1.0f) ? E32 : expf(mx);
}

// ---------------------------------------------------------------------------
// min_pool3 (3x3, stride 2, pad 1 w/ 1e5)
// ---------------------------------------------------------------------------
__global__ __launch_bounds__(256) void mp3_kernel(
    const float* __restrict__ in, float* __restrict__ out, int BC, int H) {
  int OH = H >> 1;
  int total = BC * OH * OH;
  int idx = blockIdx.x * 256 + threadIdx.x;
  if (idx >= total) return;
  int j = idx % OH, i = (idx / OH) % OH, bc = idx / (OH * OH);
  float mn = 100000.0f;
  for (int di = 0; di < 3; ++di) {
    int r = 2 * i - 1 + di;
    if (r < 0 || r >= H) continue;
    for (int dj = 0; dj < 3; ++dj) {
      int cc = 2 * j - 1 + dj;
      if (cc < 0 || cc >= H) continue;
      mn = fminf(mn, in[bc * H * H + r * H + cc]);
    }
  }
  out[idx] = mn;
}

// min_pool3 over (a*b) computed on the fly
__global__ __launch_bounds__(256) void mp3mul_kernel(
    const float* __restrict__ a, const float* __restrict__ b2,
    float* __restrict__ out, int BC, int H) {
  int OH = H >> 1;
  int total = BC * OH * OH;
  int idx = blockIdx.x * 256 + threadIdx.x;
  if (idx >= total) return;
  int j = idx % OH, i = (idx / OH) % OH, bc = idx / (OH * OH);
  float mn = 100000.0f;
  for (int di = 0; di < 3; ++di) {
    int r = 2 * i - 1 + di;
    if (r < 0 || r >= H) continue;
    for (int dj = 0; dj < 3; ++dj) {
      int cc = 2 * j - 1 + dj;
      if (cc < 0 || cc >= H) continue;
      int q = bc * H * H + r * H + cc;
      mn = fminf(mn, __fmul_rn(a[q], b2[q]));
    }
  }
  out[idx] = mn;
}

// ---------------------------------------------------------------------------
// t_conv: one block (512 threads) per patch. (unchanged from R13 — passing)
// ---------------------------------------------------------------------------
template <int CIN, int F, int S, int HIN, bool MUL>
__global__ __launch_bounds__(512, 1) void tconv_kernel(
    const float* __restrict__ in, const float* __restrict__ in2,
    const float* __restrict__ wqt, float* __restrict__ out, float MST) {
  constexpr int N = CIN * 9;
  constexpr int NP = (N <= 512) ? 512 : 1024;
  constexpr int KP = NP / 512;
  constexpr int OH = (HIN - 1) / S + 1;
  constexpr int P = OH * OH;
  constexpr int T = 512;
  constexpr int NCH = N / 32;

  __shared__ __align__(16) unsigned long long pk[NP];
  __shared__ float sval[N + 1];
  __shared__ unsigned short sidx[N];
  __shared__ float wbuf[2][32 * F];
  __shared__ float wc[NCH][F];
  __shared__ float iwc[NCH][F];
  __shared__ float pmin[F * NCH];

  int blk = blockIdx.x;
  int b = blk / P, p = blk % P;
  int ph = p / OH, pw = p % OH;
  int tid = threadIdx.x;

  // Phase 0: patch keys (+inf pad beyond N)
  for (int n = tid; n < NP; n += T) {
    if (n < N) {
      int c = n / 9, kk = n % 9, kh = kk / 3, kw = kk % 3;
      int r = ph * S + kh - 1, cc = pw * S + kw - 1;
      float v = 0.0f;
      if (r >= 0 && r < HIN && cc >= 0 && cc < HIN) {
        int q = ((b * CIN + c) * HIN + r) * HIN + cc;
        v = MUL ? __fmul_rn(in[q], in2[q]) : in[q];
      }
      pk[n] = packkey((v < 0.1f) ? MST : v, n);
    } else {
      pk[n] = ~0ull;
    }
  }
  if (tid == 0) sval[N] = 1.0f;
  __syncthreads();

  // Phase 1: bitonic sort
  if constexpr (KP == 1) {
    unsigned long long k0 = pk[tid];
    __syncthreads();
    for (int lk = 1; lk <= 9; ++lk) {
      for (int lj = lk - 1; lj >= 0; --lj) {
        int j = 1 << lj;
        bool up = ((tid >> lk) & 1) == 0;
        bool wmin = (((tid & j) == 0) == up);
        unsigned long long o;
        if (lj >= 6) {
          pk[tid] = k0;
          __syncthreads();
          o = pk[tid ^ j];
          __syncthreads();
        } else {
          o = __shfl_xor(k0, j, 64);
        }
        k0 = wmin ? (k0 < o ? k0 : o) : (k0 > o ? k0 : o);
      }
    }
    if (tid < N) {
      sval[tid] = unpackval(k0);
      sidx[tid] = (unsigned short)(k0 & 0xffffull);
    }
  } else {
    unsigned long long k0 = pk[2 * tid], k1 = pk[2 * tid + 1];
    __syncthreads();
    for (int lk = 1; lk <= 10; ++lk) {
      for (int lj = lk - 1; lj >= 0; --lj) {
        bool up = ((tid >> (lk - 1)) & 1) == 0;  // = ((i>>lk)&1)==0, i=2*tid+m
        if (lj == 0) {
          if ((k0 > k1) == up) { unsigned long long t2 = k0; k0 = k1; k1 = t2; }
        } else {
          int tj = 1 << (lj - 1);
          bool wmin = (((tid & tj) == 0) == up);
          unsigned long long o0, o1;
          if (lj >= 7) {
            pk[tid] = k0; pk[512 + tid] = k1;
            __syncthreads();
            o0 = pk[tid ^ tj]; o1 = pk[512 + (tid ^ tj)];
            __syncthreads();
          } else {
            o0 = __shfl_xor(k0, tj, 64);
            o1 = __shfl_xor(k1, tj, 64);
          }
          k0 = wmin ? (k0 < o0 ? k0 : o0) : (k0 > o0 ? k0 : o0);
          k1 = wmin ? (k1 < o1 ? k1 : o1) : (k1 > o1 ? k1 : o1);
        }
      }
    }
    int i0 = tid * 2;
    if (i0 < N) {
      sval[i0] = unpackval(k0);
      sidx[i0] = (unsigned short)(k0 & 0xffffull);
    }
    if (i0 + 1 < N) {
      sval[i0 + 1] = unpackval(k1);
      sidx[i0 + 1] = (unsigned short)(k1 & 0xffffull);
    }
  }
  __syncthreads();

  // Phase 2a: stage chunk 0 (all threads)
  for (int t = tid; t < 32 * F; t += T) {
    int q = t / F, f = t % F;
    wbuf[0][t] = wqt[(int)sidx[q] * F + f];
  }
  __syncthreads();

  // Phase 2b: pass A — wave 0 chains, other waves stage next chunk
  float wsum = 0.0f, iwsum = 0.0f;
  for (int c = 0; c < NCH; ++c) {
    if (tid >= 64 && c + 1 < NCH) {
      int i0n = (c + 1) * 32;
      float* nb = wbuf[(c + 1) & 1];
      for (int t = tid - 64; t < 32 * F; t += (T - 64)) {
        int q = t / F, f = t % F;
        nb[t] = wqt[(int)sidx[i0n + q] * F + f];
      }
    }
    if (tid < F) {
      const float* wb = wbuf[c & 1];
      wc[c][tid] = wsum;
      iwc[c][tid] = iwsum;
      int i0 = c * 32;
#pragma unroll
      for (int q0 = 0; q0 < 32; q0 += 8) {
        float w8[8], s8[8];
#pragma unroll
        for (int r = 0; r < 8; ++r) {
          w8[r] = wb[(q0 + r) * F + tid];
          s8[r] = sval[i0 + q0 + r];
        }
#pragma unroll
        for (int r = 0; r < 8; ++r) {
          wsum = __fadd_rn(wsum, w8[r]);
          iwsum = __fadd_rn(iwsum, __fmul_rn(s8[r], w8[r]));
        }
      }
    }
    __syncthreads();
  }

  // Phase 2c: replay — NCH*F parallel tasks, bit-exact per element
  for (int task = tid; task < NCH * F; task += T) {
    int c = task / F, f = task % F;
    float ws = wc[c][f], iws = iwc[c][f], omin = 3.402823466e38f;
    int i0 = c * 32;
#pragma unroll
    for (int q0 = 0; q0 < 32; q0 += 8) {
      float wv8[8], sv8[8], nv8[8];
#pragma unroll
      for (int r = 0; r < 8; ++r) {
        int i = i0 + q0 + r;
        wv8[r] = wqt[(int)sidx[i] * F + f];
        sv8[r] = sval[i];
        nv8[r] = sval[i + 1];
      }
#pragma unroll
      for (int r = 0; r < 8; ++r) {
        ws = __fadd_rn(ws, wv8[r]);
        iws = __fadd_rn(iws, __fmul_rn(sv8[r], wv8[r]));
        float den = fminf(fmaxf(__fadd_rn(ws, -1.0f), 1e-10f), 1e10f);
        float oa = iws / den;
        float o = (ws < 1.0f) ? MST : oa;
        o = (o < sv8[r]) ? MST : o;
        o = (o > nv8[r]) ? MST : o;  // t_linear_c: strict >
        omin = fminf(omin, o);
      }
    }
    pmin[f * NCH + c] = omin;
  }
  __syncthreads();

  // Phase 2d: min across chunks (order-free), write out
  if (tid < F) {
    float m2 = pmin[tid * NCH];
#pragma unroll
    for (int c = 1; c < NCH; ++c) m2 = fminf(m2, pmin[tid * NCH + c]);
    out[(b * F + tid) * P + p] = m2;
  }
}

// ---------------------------------------------------------------------------
// Bitonic pass, fully compile-time specialized (LK = stage, LJ = pass).
// (reverted to the R10/R11 unrolled form — measured faster than compact loop)
// ---------------------------------------------------------------------------
template <int LK, int LJ>
__device__ __forceinline__ void bpass(unsigned long long (&k)[8],
                                      unsigned long long* keys,
                                      int tid, int lane) {
  if constexpr (LJ >= 9) {
    constexpr int pm = 1 << (LJ - 3);
#pragma unroll
    for (int m = 0; m < 8; ++m) keys[m * 512 + tid] = k[m];
    __syncthreads();
    bool lower = ((tid & pm) == 0);
    bool up = (((tid >> (LK - 3)) & 1) == 0);
    bool wmin = (lower == up);
#pragma unroll
    for (int m = 0; m < 8; ++m) {
      unsigned long long o = keys[m * 512 + (tid ^ pm)];
      unsigned long long mine = k[m];
      k[m] = wmin ? (mine < o ? mine : o) : (mine > o ? mine : o);
    }
    __syncthreads();
  } else if constexpr (LJ >= 3) {
    constexpr int lm = 1 << (LJ - 3);
    bool lower = ((lane & lm) == 0);
    bool up = (((tid >> (LK - 3)) & 1) == 0);
    bool wmin = (lower == up);
#pragma unroll
    for (int m = 0; m < 8; ++m) {
      unsigned long long o = __shfl_xor(k[m], lm, 64);
      unsigned long long mine = k[m];
      k[m] = wmin ? (mine < o ? mine : o) : (mine > o ? mine : o);
    }
  } else {
    constexpr int j = 1 << LJ;
#pragma unroll
    for (int m = 0; m < 8; ++m) {
      if ((m & j) == 0) {
        int i = (tid << 3) + m;
        bool up = (((i >> LK) & 1) == 0);
        unsigned long long a = k[m], c2 = k[m | j];
        if ((a > c2) == up) { k[m] = c2; k[m | j] = a; }
      }
    }
  }
}

template <int LK, int LJ>
__device__ __forceinline__ void bpasses(unsigned long long (&k)[8],
                                        unsigned long long* keys,
                                        int tid, int lane) {
  bpass<LK, LJ>(k, keys, tid, lane);
  if constexpr (LJ > 0) bpasses<LK, LJ - 1>(k, keys, tid, lane);
}

template <int LK>
__device__ __forceinline__ void bstages(unsigned long long (&k)[8],
                                        unsigned long long* keys,
                                        int tid, int lane) {
  bpasses<LK, LK - 1>(k, keys, tid, lane);
  if constexpr (LK < 12) bstages<LK + 1>(k, keys, tid, lane);
}

// ---------------------------------------------------------------------------
// FC sort: 8 blocks x 512, unrolled register bitonic; writes sval/sidx.
// ---------------------------------------------------------------------------
__global__ __launch_bounds__(512, 1) void fc_sort_kernel(
    const float* __restrict__ z5, const float* __restrict__ m3,
    float* __restrict__ svalG, unsigned short* __restrict__ sidxG) {
  __shared__ __align__(16) unsigned long long keys[4096];
  int b = blockIdx.x, tid = threadIdx.x, lane = tid & 63;

  unsigned long long k[8];
  {
    int c = tid >> 3, p0 = (tid << 3) & 63;
    const float4* z4p = (const float4*)(z5 + (b * 64 + c) * 64 + p0);
    const float4* m4p = (const float4*)(m3 + (b * 32 + (c & 31)) * 64 + p0);
    float4 za = z4p[0], zb = z4p[1], ma = m4p[0], mb = m4p[1];
    int n0 = tid << 3;
    k[0] = packkey(__fmul_rn(za.x, ma.x), n0 + 0);
    k[1] = packkey(__fmul_rn(za.y, ma.y), n0 + 1);
    k[2] = packkey(__fmul_rn(za.z, ma.z), n0 + 2);
    k[3] = packkey(__fmul_rn(za.w, ma.w), n0 + 3);
    k[4] = packkey(__fmul_rn(zb.x, mb.x), n0 + 4);
    k[5] = packkey(__fmul_rn(zb.y, mb.y), n0 + 5);
    k[6] = packkey(__fmul_rn(zb.z, mb.z), n0 + 6);
    k[7] = packkey(__fmul_rn(zb.w, mb.w), n0 + 7);
  }

  bstages<1>(k, keys, tid, lane);

  {
    float4 v0, v1;
    v0.x = unpackval(k[0]); v0.y = unpackval(k[1]);
    v0.z = unpackval(k[2]); v0.w = unpackval(k[3]);
    v1.x = unpackval(k[4]); v1.y = unpackval(k[5]);
    v1.z = unpackval(k[6]); v1.w = unpackval(k[7]);
    float* svalRow = svalG + b * 4104;
    ((float4*)svalRow)[tid * 2] = v0;
    ((float4*)svalRow)[tid * 2 + 1] = v1;
    ushort si[8];
#pragma unroll
    for (int m = 0; m < 8; ++m) si[m] = (unsigned short)(k[m] & 0xffffull);
    ((ulong2*)(sidxG + b * 4096))[tid] = *(ulong2*)si;
    if (tid == 0) svalRow[4096] = 1.0f;
  }
}

// ---------------------------------------------------------------------------
// FC scan v2: 80 blocks (one per batch x neuron) x 512 threads.
//  - load sval/sidx into LDS (coalesced)
//  - stage ALL 4096 weights for this neuron into LDS (one batched pass)
//  - ONE uninterrupted exact serial chain (thread 0, carries every 32)
//  - 128-way bit-exact replay + order-free min
// ---------------------------------------------------------------------------
__global__ __launch_bounds__(512, 1) void fc_scan2_kernel(
    const float* __restrict__ svalG, const unsigned short* __restrict__ sidxG,
    const float* __restrict__ wfcT, float* __restrict__ out) {
  constexpr int NN = 4096;
  __shared__ __align__(16) float sval[NN + 1];
  __shared__ __align__(16) unsigned short sidx[NN];
  __shared__ __align__(16) float wlds[NN];
  __shared__ float wc[128], iwc[128];
  __shared__ float pmin[128];

  int blk = blockIdx.x;
  int b = blk / 10, f = blk % 10;
  int tid = threadIdx.x;
  const float* svalRow = svalG + b * 4104;

  for (int t = tid; t < 1024; t += 512)
    ((float4*)sval)[t] = ((const float4*)svalRow)[t];
  ((ulong2*)sidx)[tid] = ((const ulong2*)(sidxG + b * 4096))[tid];
  if (tid == 0) sval[NN] = svalRow[4096];
  __syncthreads();

  // stage all weights for neuron f (8 gathers/thread, all in flight)
  {
    int idx8[8];
    float tmp[8];
#pragma unroll
    for (int u = 0; u < 8; ++u) idx8[u] = sidx[tid + u * 512];
#pragma unroll
    for (int u = 0; u < 8; ++u) tmp[u] = wfcT[idx8[u] * 10 + f];
#pragma unroll
    for (int u = 0; u < 8; ++u) wlds[tid + u * 512] = tmp[u];
  }
  __syncthreads();

  // exact serial chain (thread 0), uninterrupted, carries every 32
  if (tid == 0) {
    float wsum = 0.0f, iwsum = 0.0f;
    float4 wA4[4], sA4[4], wB4[4], sB4[4];
    auto LD = [&](int i0, float4* w4, float4* s4) {
#pragma unroll
      for (int kq = 0; kq < 4; ++kq) {
        w4[kq] = *(const float4*)(wlds + i0 + 4 * kq);
        s4[kq] = *(const float4*)(sval + i0 + 4 * kq);
      }
    };
    auto ACC = [&](const float4* w4, const float4* s4) {
#pragma unroll
      for (int kq = 0; kq < 4; ++kq) {
        float w0 = w4[kq].x, w1 = w4[kq].y, w2 = w4[kq].z, w3 = w4[kq].w;
        float s0 = s4[kq].x, s1 = s4[kq].y, s2 = s4[kq].z, s3 = s4[kq].w;
        wsum = __fadd_rn(wsum, w0); iwsum = __fadd_rn(iwsum, __fmul_rn(s0, w0));
        wsum = __fadd_rn(wsum, w1); iwsum = __fadd_rn(iwsum, __fmul_rn(s1, w1));
        wsum = __fadd_rn(wsum, w2); iwsum = __fadd_rn(iwsum, __fmul_rn(s2, w2));
        wsum = __fadd_rn(wsum, w3); iwsum = __fadd_rn(iwsum, __fmul_rn(s3, w3));
      }
    };
    LD(0, wA4, sA4);
    for (int i0 = 0; i0 < NN; i0 += 32) {
      wc[i0 >> 5] = wsum;
      iwc[i0 >> 5] = iwsum;
      LD(i0 + 16, wB4, sB4);
      ACC(wA4, sA4);
      if (i0 + 32 < NN) LD(i0 + 32, wA4, sA4);
      ACC(wB4, sB4);
    }
  }
  __syncthreads();

  // replay: 128 chunks of 32, bit-exact per element
  const float MST = 4.0f * E32;
  if (tid < 128) {
    float ws = wc[tid], iws = iwc[tid], omin = 3.402823466e38f;
    int i0 = tid * 32;
    for (int q0 = 0; q0 < 32; q0 += 8) {
      float wv8[8], sv8[8], nv8[8];
#pragma unroll
      for (int r = 0; r < 8; ++r) {
        int i = i0 + q0 + r;
        wv8[r] = wlds[i];
        sv8[r] = sval[i];
        nv8[r] = sval[i + 1];
      }
#pragma unroll
      for (int r = 0; r < 8; ++r) {
        ws = __fadd_rn(ws, wv8[r]);
        iws = __fadd_rn(iws, __fmul_rn(sv8[r], wv8[r]));
        float den = fminf(fmaxf(__fadd_rn(ws, -1.0f), 1e-10f), 1e10f);
        float oa = iws / den;
        float o = (ws < 1.0f) ? MST : oa;
        o = (o < sv8[r]) ? MST : o;
        o = (o >= nv8[r]) ? MST : o;  // t_linear: >=
        omin = fminf(omin, o);
      }
    }
    pmin[tid] = omin;
  }
  __syncthreads();

  if (tid == 0) {
    float m = pmin[0];
    for (int c = 1; c < 128; ++c) m = fminf(m, pmin[c]);
    out[b * 10 + f] = m;
  }
}

// ---------------------------------------------------------------------------
extern "C" void kernel_launch(void* const* d_in, const int* in_sizes, int n_in,
                              void* d_out, int out_size, void* d_ws, size_t ws_size,
                              hipStream_t stream) {
  const float* inp   = (const float*)d_in[0];
  const float* w1    = (const float*)d_in[1];
  const float* bn_g  = (const float*)d_in[2];
  const float* bn_b  = (const float*)d_in[3];
  const float* bn_m  = (const float*)d_in[4];
  const float* bn_v  = (const float*)d_in[5];
  const float* w2    = (const float*)d_in[6];
  const float* w3    = (const float*)d_in[7];
  const float* w4    = (const float*)d_in[8];
  const float* w5    = (const float*)d_in[9];
  const float* wfc   = (const float*)d_in[10];
  float* out = (float*)d_out;

  float* ws = (float*)d_ws;
  float* wq2 = ws + 16;          // 9216
  float* wq3 = wq2 + 9216;       // 9216
  float* wq4 = wq3 + 9216;       // 18432
  float* wq5 = wq4 + 18432;      // 36864
  float* z1  = wq5 + 36864;      // 262144
  float* m1  = z1 + 262144;      // 65536
  float* z2  = m1 + 65536;       // 65536
  float* z3  = z2 + 65536;       // 65536
  float* m3  = z3 + 65536;       // 16384
  float* z4  = m3 + 16384;       // 32768
  float* z5  = z4 + 32768;       // 32768
  float* tanhbuf  = z5 + 32768;  // 73728
  float* partials = tanhbuf + 73728;  // 288 (pad 512)
  float* wfcT = partials + 512;  // 40960
  float* svalG = wfcT + 40960;   // 8*4104 = 32832
  unsigned short* sidxG = (unsigned short*)(svalG + 32832);  // 8*4096 u16

  tanh_max_kernel<<<288, 256, 0, stream>>>(w2, w3, w4, w5, tanhbuf, partials);
  quantT_kernel<<<448, 256, 0, stream>>>(tanhbuf, partials, wq2, wq3, wq4, wq5, wfc, wfcT);

  conv1_kernel<<<1024, 256, 0, stream>>>(inp, w1, bn_g, bn_b, bn_m, bn_v, z1);
  mp3_kernel<<<256, 256, 0, stream>>>(z1, m1, 8 * 32, 32);

  tconv_kernel<32, 32, 2, 32, false><<<8 * 256, 512, 0, stream>>>(z1, nullptr, wq2, z2, E32);
  tconv_kernel<32, 32, 1, 16, false><<<8 * 256, 512, 0, stream>>>(z2, nullptr, wq3, z3, E32);
  mp3mul_kernel<<<64, 256, 0, stream>>>(z3, m1, m3, 8 * 32, 16);
  tconv_kernel<32, 64, 2, 16, true><<<8 * 64, 512, 0, stream>>>(z3, m1, wq4, z4, 2.0f * E32);
  tconv_kernel<64, 64, 1, 8, false><<<8 * 64, 512, 0, stream>>>(z4, nullptr, wq5, z5, 2.0f * E32);

  fc_sort_kernel<<<8, 512, 0, stream>>>(z5, m3, svalG, sidxG);
  fc_scan2_kernel<<<80, 512, 0, stream>>>(svalG, sidxG, wfcT, out);
}

// Round 15
// 234.871 us; speedup vs baseline: 1.1291x; 1.0690x over previous
//
#include <hip/hip_runtime.h>
#include <hip/hip_bf16.h>
#include <math.h>

// float32(np.e) exactly: 0x402DF854
#define E32 2.7182817459106445f

__device__ __forceinline__ unsigned long long packkey(float vf, int idx) {
  unsigned u = __float_as_uint(vf);
  u = (u & 0x80000000u) ? ~u : (u | 0x80000000u);
  return (((unsigned long long)u) << 32) | (unsigned)idx;
}
__device__ __forceinline__ float unpackval(unsigned long long k) {
  unsigned m = (unsigned)(k >> 32);
  m = (m & 0x80000000u) ? (m ^ 0x80000000u) : ~m;
  return __uint_as_float(m);
}

// ---------------------------------------------------------------------------
// Stage 1: one tanh per thread; store tanh value + per-block max|tanh|.
// ---------------------------------------------------------------------------
__global__ __launch_bounds__(256) void tanh_max_kernel(
    const float* __restrict__ w2, const float* __restrict__ w3,
    const float* __restrict__ w4, const float* __restrict__ w5,
    float* __restrict__ tanhbuf, float* __restrict__ partials) {
  int blk = blockIdx.x;
  const float* w; int base_blk, tbase;
  if (blk < 36)       { w = w2; base_blk = 0;   tbase = 0; }
  else if (blk < 72)  { w = w3; base_blk = 36;  tbase = 9216; }
  else if (blk < 144) { w = w4; base_blk = 72;  tbase = 18432; }
  else                { w = w5; base_blk = 144; tbase = 36864; }
  int i = (blk - base_blk) * 256 + threadIdx.x;
  float t = tanhf(w[i]);
  tanhbuf[tbase + i] = t;
  __shared__ float red[256];
  red[threadIdx.x] = fabsf(t);
  __syncthreads();
  for (int s = 128; s > 0; s >>= 1) {
    if (threadIdx.x < s) red[threadIdx.x] = fmaxf(red[threadIdx.x], red[threadIdx.x + s]);
    __syncthreads();
  }
  if (threadIdx.x == 0) partials[blk] = red[0];
}

// ---------------------------------------------------------------------------
// Stage 2 (fused): blocks [0,288) quantize; blocks [288,448) transpose wfc.
// ---------------------------------------------------------------------------
__global__ __launch_bounds__(256) void quantT_kernel(
    const float* __restrict__ tanhbuf, const float* __restrict__ partials,
    float* __restrict__ q2, float* __restrict__ q3,
    float* __restrict__ q4, float* __restrict__ q5,
    const float* __restrict__ wfc, float* __restrict__ wfcT) {
  int blk = blockIdx.x;
  if (blk >= 288) {
    int o = (blk - 288) * 256 + threadIdx.x;
    if (o < 40960) {
      int n = o / 10, f = o % 10;
      wfcT[o] = wfc[f * 4096 + n];
    }
    return;
  }
  float* dst; int base_blk, tbase, pb0, pb1, F, N;
  if (blk < 36)       { dst = q2; base_blk = 0;   tbase = 0;     pb0 = 0;   pb1 = 36;  F = 32; N = 288; }
  else if (blk < 72)  { dst = q3; base_blk = 36;  tbase = 9216;  pb0 = 36;  pb1 = 72;  F = 32; N = 288; }
  else if (blk < 144) { dst = q4; base_blk = 72;  tbase = 18432; pb0 = 72;  pb1 = 144; F = 64; N = 288; }
  else                { dst = q5; base_blk = 144; tbase = 36864; pb0 = 144; pb1 = 288; F = 64; N = 576; }
  __shared__ float red[256];
  float mx = 0.0f;
  for (int j = pb0 + threadIdx.x; j < pb1; j += 256) mx = fmaxf(mx, partials[j]);
  red[threadIdx.x] = mx;
  __syncthreads();
  for (int s = 128; s > 0; s >>= 1) {
    if (threadIdx.x < s) red[threadIdx.x] = fmaxf(red[threadIdx.x], red[threadIdx.x + s]);
    __syncthreads();
  }
  float a = red[0];
  int i = (blk - base_blk) * 256 + threadIdx.x;
  float t = tanhbuf[tbase + i];
  int f = i / N, n = i % N;
  float r = fminf(fmaxf(t / a, -1.0f), 1.0f) * 127.0f;
  dst[n * F + f] = rintf(r) * a / 127.0f;
}

// ---------------------------------------------------------------------------
// conv1 + BN + ReLU + maxpool2 + min(.,1) + exp
// ---------------------------------------------------------------------------
__global__ __launch_bounds__(256) void conv1_kernel(
    const float* __restrict__ inp, const float* __restrict__ w,
    const float* __restrict__ g, const float* __restrict__ bb,
    const float* __restrict__ m, const float* __restrict__ vv,
    float* __restrict__ z1) {
  int idx = blockIdx.x * 256 + threadIdx.x;
  if (idx >= 8 * 32 * 32 * 32) return;
  int x = idx & 31, y = (idx >> 5) & 31, c = (idx >> 10) & 31, b = idx >> 15;
  float scale = g[c] / sqrtf(vv[c] + 1e-5f);
  float bias = bb[c];
  float mean = m[c];
  float mx = -3.402823466e38f;
  for (int dy = 0; dy < 2; ++dy) {
    for (int dx = 0; dx < 2; ++dx) {
      int oy = 2 * y + dy, ox = 2 * x + dx;
      float acc = 0.0f;
      for (int kh = 0; kh < 5; ++kh) {
        int r = oy + kh - 2;
        if (r < 0 || r >= 64) continue;
        for (int kw = 0; kw < 5; ++kw) {
          int cc2 = ox + kw - 2;
          if (cc2 < 0 || cc2 >= 64) continue;
          acc += w[c * 25 + kh * 5 + kw] * inp[(b * 64 + r) * 64 + cc2];
        }
      }
      float xs = (acc - mean) * scale + bias;
      xs = fmaxf(xs, 0.0f);
      mx = fmaxf(mx, xs);
    }
  }
  mx = fminf(mx, 1.0f);
  z1[idx] = (mx == 1.0f) ? E32 : expf(mx);
}

// ---------------------------------------------------------------------------
// min_pool3 (3x3, stride 2, pad 1 w/ 1e5)
// ---------------------------------------------------------------------------
__global__ __launch_bounds__(256) void mp3_kernel(
    const float* __restrict__ in, float* __restrict__ out, int BC, int H) {
  int OH = H >> 1;
  int total = BC * OH * OH;
  int idx = blockIdx.x * 256 + threadIdx.x;
  if (idx >= total) return;
  int j = idx % OH, i = (idx / OH) % OH, bc = idx / (OH * OH);
  float mn = 100000.0f;
  for (int di = 0; di < 3; ++di) {
    int r = 2 * i - 1 + di;
    if (r < 0 || r >= H) continue;
    for (int dj = 0; dj < 3; ++dj) {
      int cc = 2 * j - 1 + dj;
      if (cc < 0 || cc >= H) continue;
      mn = fminf(mn, in[bc * H * H + r * H + cc]);
    }
  }
  out[idx] = mn;
}

// min_pool3 over (a*b) computed on the fly
__global__ __launch_bounds__(256) void mp3mul_kernel(
    const float* __restrict__ a, const float* __restrict__ b2,
    float* __restrict__ out, int BC, int H) {
  int OH = H >> 1;
  int total = BC * OH * OH;
  int idx = blockIdx.x * 256 + threadIdx.x;
  if (idx >= total) return;
  int j = idx % OH, i = (idx / OH) % OH, bc = idx / (OH * OH);
  float mn = 100000.0f;
  for (int di = 0; di < 3; ++di) {
    int r = 2 * i - 1 + di;
    if (r < 0 || r >= H) continue;
    for (int dj = 0; dj < 3; ++dj) {
      int cc = 2 * j - 1 + dj;
      if (cc < 0 || cc >= H) continue;
      int q = bc * H * H + r * H + cc;
      mn = fminf(mn, __fmul_rn(a[q], b2[q]));
    }
  }
  out[idx] = mn;
}

// ---------------------------------------------------------------------------
// t_conv: one block (512 threads) per patch. (unchanged — passing)
// ---------------------------------------------------------------------------
template <int CIN, int F, int S, int HIN, bool MUL>
__global__ __launch_bounds__(512, 1) void tconv_kernel(
    const float* __restrict__ in, const float* __restrict__ in2,
    const float* __restrict__ wqt, float* __restrict__ out, float MST) {
  constexpr int N = CIN * 9;
  constexpr int NP = (N <= 512) ? 512 : 1024;
  constexpr int KP = NP / 512;
  constexpr int OH = (HIN - 1) / S + 1;
  constexpr int P = OH * OH;
  constexpr int T = 512;
  constexpr int NCH = N / 32;

  __shared__ __align__(16) unsigned long long pk[NP];
  __shared__ float sval[N + 1];
  __shared__ unsigned short sidx[N];
  __shared__ float wbuf[2][32 * F];
  __shared__ float wc[NCH][F];
  __shared__ float iwc[NCH][F];
  __shared__ float pmin[F * NCH];

  int blk = blockIdx.x;
  int b = blk / P, p = blk % P;
  int ph = p / OH, pw = p % OH;
  int tid = threadIdx.x;

  // Phase 0: patch keys (+inf pad beyond N)
  for (int n = tid; n < NP; n += T) {
    if (n < N) {
      int c = n / 9, kk = n % 9, kh = kk / 3, kw = kk % 3;
      int r = ph * S + kh - 1, cc = pw * S + kw - 1;
      float v = 0.0f;
      if (r >= 0 && r < HIN && cc >= 0 && cc < HIN) {
        int q = ((b * CIN + c) * HIN + r) * HIN + cc;
        v = MUL ? __fmul_rn(in[q], in2[q]) : in[q];
      }
      pk[n] = packkey((v < 0.1f) ? MST : v, n);
    } else {
      pk[n] = ~0ull;
    }
  }
  if (tid == 0) sval[N] = 1.0f;
  __syncthreads();

  // Phase 1: bitonic sort
  if constexpr (KP == 1) {
    unsigned long long k0 = pk[tid];
    __syncthreads();
    for (int lk = 1; lk <= 9; ++lk) {
      for (int lj = lk - 1; lj >= 0; --lj) {
        int j = 1 << lj;
        bool up = ((tid >> lk) & 1) == 0;
        bool wmin = (((tid & j) == 0) == up);
        unsigned long long o;
        if (lj >= 6) {
          pk[tid] = k0;
          __syncthreads();
          o = pk[tid ^ j];
          __syncthreads();
        } else {
          o = __shfl_xor(k0, j, 64);
        }
        k0 = wmin ? (k0 < o ? k0 : o) : (k0 > o ? k0 : o);
      }
    }
    if (tid < N) {
      sval[tid] = unpackval(k0);
      sidx[tid] = (unsigned short)(k0 & 0xffffull);
    }
  } else {
    unsigned long long k0 = pk[2 * tid], k1 = pk[2 * tid + 1];
    __syncthreads();
    for (int lk = 1; lk <= 10; ++lk) {
      for (int lj = lk - 1; lj >= 0; --lj) {
        bool up = ((tid >> (lk - 1)) & 1) == 0;  // = ((i>>lk)&1)==0, i=2*tid+m
        if (lj == 0) {
          if ((k0 > k1) == up) { unsigned long long t2 = k0; k0 = k1; k1 = t2; }
        } else {
          int tj = 1 << (lj - 1);
          bool wmin = (((tid & tj) == 0) == up);
          unsigned long long o0, o1;
          if (lj >= 7) {
            pk[tid] = k0; pk[512 + tid] = k1;
            __syncthreads();
            o0 = pk[tid ^ tj]; o1 = pk[512 + (tid ^ tj)];
            __syncthreads();
          } else {
            o0 = __shfl_xor(k0, tj, 64);
            o1 = __shfl_xor(k1, tj, 64);
          }
          k0 = wmin ? (k0 < o0 ? k0 : o0) : (k0 > o0 ? k0 : o0);
          k1 = wmin ? (k1 < o1 ? k1 : o1) : (k1 > o1 ? k1 : o1);
        }
      }
    }
    int i0 = tid * 2;
    if (i0 < N) {
      sval[i0] = unpackval(k0);
      sidx[i0] = (unsigned short)(k0 & 0xffffull);
    }
    if (i0 + 1 < N) {
      sval[i0 + 1] = unpackval(k1);
      sidx[i0 + 1] = (unsigned short)(k1 & 0xffffull);
    }
  }
  __syncthreads();

  // Phase 2a: stage chunk 0 (all threads)
  for (int t = tid; t < 32 * F; t += T) {
    int q = t / F, f = t % F;
    wbuf[0][t] = wqt[(int)sidx[q] * F + f];
  }
  __syncthreads();

  // Phase 2b: pass A — wave 0 chains, other waves stage next chunk
  float wsum = 0.0f, iwsum = 0.0f;
  for (int c = 0; c < NCH; ++c) {
    if (tid >= 64 && c + 1 < NCH) {
      int i0n = (c + 1) * 32;
      float* nb = wbuf[(c + 1) & 1];
      for (int t = tid - 64; t < 32 * F; t += (T - 64)) {
        int q = t / F, f = t % F;
        nb[t] = wqt[(int)sidx[i0n + q] * F + f];
      }
    }
    if (tid < F) {
      const float* wb = wbuf[c & 1];
      wc[c][tid] = wsum;
      iwc[c][tid] = iwsum;
      int i0 = c * 32;
#pragma unroll
      for (int q0 = 0; q0 < 32; q0 += 8) {
        float w8[8], s8[8];
#pragma unroll
        for (int r = 0; r < 8; ++r) {
          w8[r] = wb[(q0 + r) * F + tid];
          s8[r] = sval[i0 + q0 + r];
        }
#pragma unroll
        for (int r = 0; r < 8; ++r) {
          wsum = __fadd_rn(wsum, w8[r]);
          iwsum = __fadd_rn(iwsum, __fmul_rn(s8[r], w8[r]));
        }
      }
    }
    __syncthreads();
  }

  // Phase 2c: replay — NCH*F parallel tasks, bit-exact per element
  for (int task = tid; task < NCH * F; task += T) {
    int c = task / F, f = task % F;
    float ws = wc[c][f], iws = iwc[c][f], omin = 3.402823466e38f;
    int i0 = c * 32;
#pragma unroll
    for (int q0 = 0; q0 < 32; q0 += 8) {
      float wv8[8], sv8[8], nv8[8];
#pragma unroll
      for (int r = 0; r < 8; ++r) {
        int i = i0 + q0 + r;
        wv8[r] = wqt[(int)sidx[i] * F + f];
        sv8[r] = sval[i];
        nv8[r] = sval[i + 1];
      }
#pragma unroll
      for (int r = 0; r < 8; ++r) {
        ws = __fadd_rn(ws, wv8[r]);
        iws = __fadd_rn(iws, __fmul_rn(sv8[r], wv8[r]));
        float den = fminf(fmaxf(__fadd_rn(ws, -1.0f), 1e-10f), 1e10f);
        float oa = iws / den;
        float o = (ws < 1.0f) ? MST : oa;
        o = (o < sv8[r]) ? MST : o;
        o = (o > nv8[r]) ? MST : o;  // t_linear_c: strict >
        omin = fminf(omin, o);
      }
    }
    pmin[f * NCH + c] = omin;
  }
  __syncthreads();

  // Phase 2d: min across chunks (order-free), write out
  if (tid < F) {
    float m2 = pmin[tid * NCH];
#pragma unroll
    for (int c = 1; c < NCH; ++c) m2 = fminf(m2, pmin[tid * NCH + c]);
    out[(b * F + tid) * P + p] = m2;
  }
}

// ---------------------------------------------------------------------------
// Bitonic pass, fully compile-time specialized (LK = stage, LJ = pass).
// ---------------------------------------------------------------------------
template <int LK, int LJ>
__device__ __forceinline__ void bpass(unsigned long long (&k)[8],
                                      unsigned long long* keys,
                                      int tid, int lane) {
  if constexpr (LJ >= 9) {
    constexpr int pm = 1 << (LJ - 3);
#pragma unroll
    for (int m = 0; m < 8; ++m) keys[m * 512 + tid] = k[m];
    __syncthreads();
    bool lower = ((tid & pm) == 0);
    bool up = (((tid >> (LK - 3)) & 1) == 0);
    bool wmin = (lower == up);
#pragma unroll
    for (int m = 0; m < 8; ++m) {
      unsigned long long o = keys[m * 512 + (tid ^ pm)];
      unsigned long long mine = k[m];
      k[m] = wmin ? (mine < o ? mine : o) : (mine > o ? mine : o);
    }
    __syncthreads();
  } else if constexpr (LJ >= 3) {
    constexpr int lm = 1 << (LJ - 3);
    bool lower = ((lane & lm) == 0);
    bool up = (((tid >> (LK - 3)) & 1) == 0);
    bool wmin = (lower == up);
#pragma unroll
    for (int m = 0; m < 8; ++m) {
      unsigned long long o = __shfl_xor(k[m], lm, 64);
      unsigned long long mine = k[m];
      k[m] = wmin ? (mine < o ? mine : o) : (mine > o ? mine : o);
    }
  } else {
    constexpr int j = 1 << LJ;
#pragma unroll
    for (int m = 0; m < 8; ++m) {
      if ((m & j) == 0) {
        int i = (tid << 3) + m;
        bool up = (((i >> LK) & 1) == 0);
        unsigned long long a = k[m], c2 = k[m | j];
        if ((a > c2) == up) { k[m] = c2; k[m | j] = a; }
      }
    }
  }
}

template <int LK, int LJ>
__device__ __forceinline__ void bpasses(unsigned long long (&k)[8],
                                        unsigned long long* keys,
                                        int tid, int lane) {
  bpass<LK, LJ>(k, keys, tid, lane);
  if constexpr (LJ > 0) bpasses<LK, LJ - 1>(k, keys, tid, lane);
}

template <int LK>
__device__ __forceinline__ void bstages(unsigned long long (&k)[8],
                                        unsigned long long* keys,
                                        int tid, int lane) {
  bpasses<LK, LK - 1>(k, keys, tid, lane);
  if constexpr (LK < 12) bstages<LK + 1>(k, keys, tid, lane);
}

// ---------------------------------------------------------------------------
// FC sort: 8 blocks x 512, unrolled register bitonic; writes sval/sidx.
// ---------------------------------------------------------------------------
__global__ __launch_bounds__(512, 1) void fc_sort_kernel(
    const float* __restrict__ z5, const float* __restrict__ m3,
    float* __restrict__ svalG, unsigned short* __restrict__ sidxG) {
  __shared__ __align__(16) unsigned long long keys[4096];
  int b = blockIdx.x, tid = threadIdx.x, lane = tid & 63;

  unsigned long long k[8];
  {
    int c = tid >> 3, p0 = (tid << 3) & 63;
    const float4* z4p = (const float4*)(z5 + (b * 64 + c) * 64 + p0);
    const float4* m4p = (const float4*)(m3 + (b * 32 + (c & 31)) * 64 + p0);
    float4 za = z4p[0], zb = z4p[1], ma = m4p[0], mb = m4p[1];
    int n0 = tid << 3;
    k[0] = packkey(__fmul_rn(za.x, ma.x), n0 + 0);
    k[1] = packkey(__fmul_rn(za.y, ma.y), n0 + 1);
    k[2] = packkey(__fmul_rn(za.z, ma.z), n0 + 2);
    k[3] = packkey(__fmul_rn(za.w, ma.w), n0 + 3);
    k[4] = packkey(__fmul_rn(zb.x, mb.x), n0 + 4);
    k[5] = packkey(__fmul_rn(zb.y, mb.y), n0 + 5);
    k[6] = packkey(__fmul_rn(zb.z, mb.z), n0 + 6);
    k[7] = packkey(__fmul_rn(zb.w, mb.w), n0 + 7);
  }

  bstages<1>(k, keys, tid, lane);

  {
    float4 v0, v1;
    v0.x = unpackval(k[0]); v0.y = unpackval(k[1]);
    v0.z = unpackval(k[2]); v0.w = unpackval(k[3]);
    v1.x = unpackval(k[4]); v1.y = unpackval(k[5]);
    v1.z = unpackval(k[6]); v1.w = unpackval(k[7]);
    float* svalRow = svalG + b * 4104;
    ((float4*)svalRow)[tid * 2] = v0;
    ((float4*)svalRow)[tid * 2 + 1] = v1;
    ushort si[8];
#pragma unroll
    for (int m = 0; m < 8; ++m) si[m] = (unsigned short)(k[m] & 0xffffull);
    ((ulong2*)(sidxG + b * 4096))[tid] = *(ulong2*)si;
    if (tid == 0) svalRow[4096] = 1.0f;
  }
}

// ---------------------------------------------------------------------------
// FC scan v3: 80 blocks (batch x neuron) x 512 threads.
//  - sval -> LDS; indices -> registers (one coalesced ulong2/thread)
//  - parallel precompute of interleaved pairs (w, mul=fmul(sval,w)) in LDS
//  - chain: ONE contiguous stream, full-chunk A/B register double-buffer,
//    exactly 2 fadds per element on the critical path
//  - 128-way bit-exact replay (reuses the identical mul values) + min
// ---------------------------------------------------------------------------
__global__ __launch_bounds__(512, 1) void fc_scan2_kernel(
    const float* __restrict__ svalG, const unsigned short* __restrict__ sidxG,
    const float* __restrict__ wfcT, float* __restrict__ out) {
  constexpr int NN = 4096;
  __shared__ __align__(16) float sval[NN + 1];   // 16.4 KB
  __shared__ __align__(16) float pairs[NN * 2];  // (w,mul) interleaved, 32 KB
  __shared__ float wc[128], iwc[128];
  __shared__ float pmin[128];

  int blk = blockIdx.x;
  int b = blk / 10, f = blk % 10;
  int tid = threadIdx.x;
  const float* svalRow = svalG + b * 4104;

  // sval -> LDS (coalesced float4)
  for (int t = tid; t < 1024; t += 512)
    ((float4*)sval)[t] = ((const float4*)svalRow)[t];
  if (tid == 0) sval[NN] = svalRow[4096];

  // indices -> registers (8/thread), gather weights (all in flight)
  ushort si[8];
  *(ulong2*)si = ((const ulong2*)(sidxG + b * 4096))[tid];
  float wv[8];
#pragma unroll
  for (int u = 0; u < 8; ++u) wv[u] = wfcT[(int)si[u] * 10 + f];
  __syncthreads();  // sval ready

  // pairs[2i]=w_i, pairs[2i+1]=fmul(sval_i, w_i)  (bit-identical to chain's mul)
  {
    int n0 = tid * 8;
    float4 pw[4];
#pragma unroll
    for (int u = 0; u < 4; ++u) {
      float wa = wv[2 * u], wb2 = wv[2 * u + 1];
      pw[u].x = wa;
      pw[u].y = __fmul_rn(sval[n0 + 2 * u], wa);
      pw[u].z = wb2;
      pw[u].w = __fmul_rn(sval[n0 + 2 * u + 1], wb2);
    }
#pragma unroll
    for (int u = 0; u < 4; ++u) ((float4*)pairs)[tid * 4 + u] = pw[u];
  }
  __syncthreads();

  // serial chain: 2 fadds/element, single contiguous stream, A/B full-chunk
  if (tid == 0) {
    float wsum = 0.0f, iwsum = 0.0f;
    float4 A[16], B[16];
    auto LD_A = [&](int c) {
      const float4* p4 = (const float4*)pairs + c * 16;
#pragma unroll
      for (int q = 0; q < 16; ++q) A[q] = p4[q];
    };
    auto LD_B = [&](int c) {
      const float4* p4 = (const float4*)pairs + c * 16;
#pragma unroll
      for (int q = 0; q < 16; ++q) B[q] = p4[q];
    };
    auto ACC_A = [&]() {
#pragma unroll
      for (int q = 0; q < 16; ++q) {
        wsum = __fadd_rn(wsum, A[q].x); iwsum = __fadd_rn(iwsum, A[q].y);
        wsum = __fadd_rn(wsum, A[q].z); iwsum = __fadd_rn(iwsum, A[q].w);
      }
    };
    auto ACC_B = [&]() {
#pragma unroll
      for (int q = 0; q < 16; ++q) {
        wsum = __fadd_rn(wsum, B[q].x); iwsum = __fadd_rn(iwsum, B[q].y);
        wsum = __fadd_rn(wsum, B[q].z); iwsum = __fadd_rn(iwsum, B[q].w);
      }
    };
    LD_A(0);
    for (int c = 0; c < 128; c += 2) {
      wc[c] = wsum; iwc[c] = iwsum;
      if (c + 1 < 128) LD_B(c + 1);
      ACC_A();
      wc[c + 1] = wsum; iwc[c + 1] = iwsum;
      if (c + 2 < 128) LD_A(c + 2);
      ACC_B();
    }
  }
  __syncthreads();

  // replay: 128 chunks of 32, bit-exact per element
  const float MST = 4.0f * E32;
  if (tid < 128) {
    float ws = wc[tid], iws = iwc[tid], omin = 3.402823466e38f;
    int i0 = tid * 32;
    for (int q0 = 0; q0 < 32; q0 += 8) {
      float w8[8], m8[8], sv8[8], nv8[8];
#pragma unroll
      for (int r = 0; r < 8; ++r) {
        int i = i0 + q0 + r;
        w8[r] = pairs[2 * i];
        m8[r] = pairs[2 * i + 1];
        sv8[r] = sval[i];
        nv8[r] = sval[i + 1];
      }
#pragma unroll
      for (int r = 0; r < 8; ++r) {
        ws = __fadd_rn(ws, w8[r]);
        iws = __fadd_rn(iws, m8[r]);
        float den = fminf(fmaxf(__fadd_rn(ws, -1.0f), 1e-10f), 1e10f);
        float oa = iws / den;
        float o = (ws < 1.0f) ? MST : oa;
        o = (o < sv8[r]) ? MST : o;
        o = (o >= nv8[r]) ? MST : o;  // t_linear: >=
        omin = fminf(omin, o);
      }
    }
    pmin[tid] = omin;
  }
  __syncthreads();

  if (tid == 0) {
    float m = pmin[0];
    for (int c = 1; c < 128; ++c) m = fminf(m, pmin[c]);
    out[b * 10 + f] = m;
  }
}

// ---------------------------------------------------------------------------
extern "C" void kernel_launch(void* const* d_in, const int* in_sizes, int n_in,
                              void* d_out, int out_size, void* d_ws, size_t ws_size,
                              hipStream_t stream) {
  const float* inp   = (const float*)d_in[0];
  const float* w1    = (const float*)d_in[1];
  const float* bn_g  = (const float*)d_in[2];
  const float* bn_b  = (const float*)d_in[3];
  const float* bn_m  = (const float*)d_in[4];
  const float* bn_v  = (const float*)d_in[5];
  const float* w2    = (const float*)d_in[6];
  const float* w3    = (const float*)d_in[7];
  const float* w4    = (const float*)d_in[8];
  const float* w5    = (const float*)d_in[9];
  const float* wfc   = (const float*)d_in[10];
  float* out = (float*)d_out;

  float* ws = (float*)d_ws;
  float* wq2 = ws + 16;          // 9216
  float* wq3 = wq2 + 9216;       // 9216
  float* wq4 = wq3 + 9216;       // 18432
  float* wq5 = wq4 + 18432;      // 36864
  float* z1  = wq5 + 36864;      // 262144
  float* m1  = z1 + 262144;      // 65536
  float* z2  = m1 + 65536;       // 65536
  float* z3  = z2 + 65536;       // 65536
  float* m3  = z3 + 65536;       // 16384
  float* z4  = m3 + 16384;       // 32768
  float* z5  = z4 + 32768;       // 32768
  float* tanhbuf  = z5 + 32768;  // 73728
  float* partials = tanhbuf + 73728;  // 288 (pad 512)
  float* wfcT = partials + 512;  // 40960
  float* svalG = wfcT + 40960;   // 8*4104 = 32832
  unsigned short* sidxG = (unsigned short*)(svalG + 32832);  // 8*4096 u16

  tanh_max_kernel<<<288, 256, 0, stream>>>(w2, w3, w4, w5, tanhbuf, partials);
  quantT_kernel<<<448, 256, 0, stream>>>(tanhbuf, partials, wq2, wq3, wq4, wq5, wfc, wfcT);

  conv1_kernel<<<1024, 256, 0, stream>>>(inp, w1, bn_g, bn_b, bn_m, bn_v, z1);
  mp3_kernel<<<256, 256, 0, stream>>>(z1, m1, 8 * 32, 32);

  tconv_kernel<32, 32, 2, 32, false><<<8 * 256, 512, 0, stream>>>(z1, nullptr, wq2, z2, E32);
  tconv_kernel<32, 32, 1, 16, false><<<8 * 256, 512, 0, stream>>>(z2, nullptr, wq3, z3, E32);
  mp3mul_kernel<<<64, 256, 0, stream>>>(z3, m1, m3, 8 * 32, 16);
  tconv_kernel<32, 64, 2, 16, true><<<8 * 64, 512, 0, stream>>>(z3, m1, wq4, z4, 2.0f * E32);
  tconv_kernel<64, 64, 1, 8, false><<<8 * 64, 512, 0, stream>>>(z4, nullptr, wq5, z5, 2.0f * E32);

  fc_sort_kernel<<<8, 512, 0, stream>>>(z5, m3, svalG, sidxG);
  fc_scan2_kernel<<<80, 512, 0, stream>>>(svalG, sidxG, wfcT, out);
}